// Round 1
// baseline (1769.253 us; speedup 1.0000x reference)
//
#include <hip/hip_runtime.h>
#include <hip/hip_bf16.h>

#define GEN_EPS 1e-7f

// ---------------------------------------------------------------------------
// h = relu(LayerNorm(x)) stored as bf16.  One wave per row (C=128, 2 ch/lane).
// ---------------------------------------------------------------------------
__global__ void ln_relu_kernel(const float* __restrict__ x, const float* __restrict__ g,
                               const float* __restrict__ b, __hip_bfloat16* __restrict__ h,
                               int M) {
  int lane = threadIdx.x & 63;
  int r = blockIdx.x * 4 + (threadIdx.x >> 6);
  if (r >= M) return;
  float2 v = ((const float2*)(x + (size_t)r * 128))[lane];
  float s = v.x + v.y;
#pragma unroll
  for (int o = 32; o; o >>= 1) s += __shfl_xor(s, o);
  float m = s * (1.0f / 128.0f);
  float dx = v.x - m, dy = v.y - m;
  float q = dx * dx + dy * dy;
#pragma unroll
  for (int o = 32; o; o >>= 1) q += __shfl_xor(q, o);
  float rstd = rsqrtf(q * (1.0f / 128.0f) + 1e-5f);
  float2 gv = ((const float2*)g)[lane], bv = ((const float2*)b)[lane];
  float2 hv;
  hv.x = fmaxf(fmaf(dx * rstd, gv.x, bv.x), 0.0f);
  hv.y = fmaxf(fmaf(dy * rstd, gv.y, bv.y), 0.0f);
  ((__hip_bfloat162*)(h + (size_t)r * 128))[lane] = __float22bfloat162_rn(hv);
}

// ---------------------------------------------------------------------------
// CSR construction: count -> scan -> fill
// ---------------------------------------------------------------------------
__global__ void count_kernel(const int* __restrict__ dst, int* __restrict__ counts, int nnz) {
  int i = blockIdx.x * blockDim.x + threadIdx.x;
  if (i < nnz) atomicAdd(&counts[dst[i]], 1);
}

__global__ void scan_block_sums(const int* __restrict__ counts, int* __restrict__ bsums, int M) {
  __shared__ int sm[256];
  int t = threadIdx.x;
  int base = blockIdx.x * 1024 + t * 4;
  int s = 0;
#pragma unroll
  for (int i = 0; i < 4; i++) {
    int idx = base + i;
    if (idx < M) s += counts[idx];
  }
  sm[t] = s;
  __syncthreads();
  for (int o = 128; o; o >>= 1) {
    if (t < o) sm[t] += sm[t + o];
    __syncthreads();
  }
  if (t == 0) bsums[blockIdx.x] = sm[0];
}

__global__ void scan_serial(int* bsums, int nb) {
  int acc = 0;
  for (int i = 0; i < nb; i++) {
    int v = bsums[i];
    bsums[i] = acc;
    acc += v;
  }
}

__global__ void scan_write(const int* __restrict__ counts, const int* __restrict__ bsums,
                           int* __restrict__ off, int* __restrict__ cursor, int M, int nnz) {
  __shared__ int sm[256];
  int t = threadIdx.x;
  int base = blockIdx.x * 1024 + t * 4;
  int c[4];
  int s = 0;
#pragma unroll
  for (int i = 0; i < 4; i++) {
    int idx = base + i;
    c[i] = (idx < M) ? counts[idx] : 0;
    s += c[i];
  }
  sm[t] = s;
  __syncthreads();
  for (int o = 1; o < 256; o <<= 1) {
    int v = (t >= o) ? sm[t - o] : 0;
    __syncthreads();
    sm[t] += v;
    __syncthreads();
  }
  int p = bsums[blockIdx.x] + sm[t] - s;  // exclusive prefix for this thread's 4 items
#pragma unroll
  for (int i = 0; i < 4; i++) {
    int idx = base + i;
    if (idx < M) {
      off[idx] = p;
      cursor[idx] = p;
      p += c[i];
    }
  }
  if (blockIdx.x == 0 && t == 0) off[M] = nnz;
}

__global__ void fill_kernel(const int* __restrict__ src, const int* __restrict__ dst,
                            int* __restrict__ cursor, int* __restrict__ csr_src,
                            int* __restrict__ csr_eid, int nnz) {
  int i = blockIdx.x * blockDim.x + threadIdx.x;
  if (i >= nnz) return;
  int d = dst[i];
  int p = atomicAdd(&cursor[d], 1);
  csr_src[p] = src[i];
  csr_eid[p] = i;
}

// ---------------------------------------------------------------------------
// Fused GENConv body, 16 rows per 256-thread block:
//   phase 1: per-dst softmax aggregation (CSR gather; max-shift cancels) + h
//   phase 2: hid = y @ W1 + b1     (hidden 16x256 kept in LDS)
//   LN(256) + relu
//   phase 3: out = hid @ W2 + b2 + x  (res+ residual)
// ---------------------------------------------------------------------------
template <bool HAS_EATTR>
__global__ __launch_bounds__(256) void genconv_kernel(
    const float* __restrict__ x, const __hip_bfloat16* __restrict__ h,
    const int* __restrict__ off, const int* __restrict__ csr_src,
    const int* __restrict__ csr_eid, const float* __restrict__ eattr,
    const float* __restrict__ tptr, const float* __restrict__ W1,
    const float* __restrict__ b1, const float* __restrict__ lng,
    const float* __restrict__ lnb, const float* __restrict__ W2,
    const float* __restrict__ b2, float* __restrict__ out, int M) {
  __shared__ float y[16][128];
  __shared__ float hid[16][256];
  __shared__ float stats[16][2];
  const int tid = threadIdx.x, lane = tid & 63, wv = tid >> 6;
  const int row0 = blockIdx.x * 16;
  const float t = tptr[0];

  // ---- phase 1: aggregation, one wave per row, 2 channels per lane ----
  for (int rr = wv; rr < 16; rr += 4) {
    int r = row0 + rr;
    if (r >= M) {
      y[rr][2 * lane] = 0.0f;
      y[rr][2 * lane + 1] = 0.0f;
      continue;
    }
    float2 hv = __bfloat1622float2(((const __hip_bfloat162*)(h + (size_t)r * 128))[lane]);
    int e0 = off[r], e1 = off[r + 1];
    float d0 = 0.0f, d1 = 0.0f, a0 = 0.0f, a1 = 0.0f;
    for (int e = e0; e < e1; e++) {
      int sidx = csr_src[e];
      float2 mv = __bfloat1622float2(((const __hip_bfloat162*)(h + (size_t)sidx * 128))[lane]);
      if (HAS_EATTR) {
        int id = csr_eid[e];
        float2 ea = ((const float2*)(eattr + (size_t)id * 128))[lane];
        mv.x += ea.x;
        mv.y += ea.y;
      }
      float m0 = fmaxf(mv.x, 0.0f) + GEN_EPS;
      float m1 = fmaxf(mv.y, 0.0f) + GEN_EPS;
      float al0 = __expf(m0 * t), al1 = __expf(m1 * t);
      d0 += al0;
      d1 += al1;
      a0 = fmaf(al0, m0, a0);
      a1 = fmaf(al1, m1, a1);
    }
    float y0 = (e1 > e0 ? a0 / d0 : 0.0f) + hv.x;
    float y1 = (e1 > e0 ? a1 / d1 : 0.0f) + hv.y;
    y[rr][2 * lane] = y0;
    y[rr][2 * lane + 1] = y1;
  }
  __syncthreads();

  // ---- phase 2: hid = y @ W1 + b1 (thread tid owns hidden column tid) ----
  {
    float acc[16];
#pragma unroll
    for (int r = 0; r < 16; r++) acc[r] = 0.0f;
    for (int k = 0; k < 128; k++) {
      float w = W1[k * 256 + tid];
#pragma unroll
      for (int r = 0; r < 16; r++) acc[r] = fmaf(y[r][k], w, acc[r]);
    }
    float bb = b1[tid];
#pragma unroll
    for (int r = 0; r < 16; r++) hid[r][tid] = acc[r] + bb;
  }
  __syncthreads();

  // ---- LN stats over 256 per row (one wave per row, 4 elems per lane) ----
  for (int rr = wv; rr < 16; rr += 4) {
    float v0 = hid[rr][lane], v1 = hid[rr][lane + 64];
    float v2 = hid[rr][lane + 128], v3 = hid[rr][lane + 192];
    float s = v0 + v1 + v2 + v3;
#pragma unroll
    for (int o = 32; o; o >>= 1) s += __shfl_xor(s, o);
    float m = s * (1.0f / 256.0f);
    float q = (v0 - m) * (v0 - m) + (v1 - m) * (v1 - m) + (v2 - m) * (v2 - m) +
              (v3 - m) * (v3 - m);
#pragma unroll
    for (int o = 32; o; o >>= 1) q += __shfl_xor(q, o);
    if (lane == 0) {
      stats[rr][0] = m;
      stats[rr][1] = rsqrtf(q * (1.0f / 256.0f) + 1e-5f);
    }
  }
  __syncthreads();

  // ---- normalize + relu ----
  {
    float g = lng[tid], bb = lnb[tid];
#pragma unroll
    for (int r = 0; r < 16; r++) {
      float hv = (hid[r][tid] - stats[r][0]) * stats[r][1];
      hid[r][tid] = fmaxf(fmaf(hv, g, bb), 0.0f);
    }
  }
  __syncthreads();

  // ---- phase 3: out = hid @ W2 + b2 + x; two half-K partials per column ----
  {
    int c = tid & 127, half = tid >> 7;
    float acc[16];
#pragma unroll
    for (int r = 0; r < 16; r++) acc[r] = 0.0f;
    int k0 = half * 128;
    for (int k = k0; k < k0 + 128; k++) {
      float w = W2[k * 128 + c];
#pragma unroll
      for (int r = 0; r < 16; r++) acc[r] = fmaf(hid[r][k], w, acc[r]);
    }
    __syncthreads();
    if (half == 0) {
#pragma unroll
      for (int r = 0; r < 16; r++) y[r][c] = acc[r];
    }
    __syncthreads();
    if (half == 1) {
      float bb = b2[c];
#pragma unroll
      for (int r = 0; r < 16; r++) {
        int row = row0 + r;
        if (row < M)
          out[(size_t)row * 128 + c] = y[r][c] + acc[r] + bb + x[(size_t)row * 128 + c];
      }
    }
  }
}

// ---------------------------------------------------------------------------
extern "C" void kernel_launch(void* const* d_in, const int* in_sizes, int n_in,
                              void* d_out, int out_size, void* d_ws, size_t ws_size,
                              hipStream_t stream) {
  const int C = 128;
  const float* v_x = (const float*)d_in[0];
  const float* e_x = (const float*)d_in[1];
  const int* v_ei = (const int*)d_in[2];
  const int* e_ei = (const int*)d_in[3];
  const int N = in_sizes[0] / C;
  const int E = in_sizes[1] / C;
  const int LE = in_sizes[3] / 2;

  // params: 0 pre_g, 1 pre_b, 2 t, 3 W1, 4 b1, 5 ln_g, 6 ln_b, 7 W2, 8 b2
  const float* ep[9];
  const float* np_[9];
  for (int i = 0; i < 9; i++) ep[i] = (const float*)d_in[4 + i];
  for (int i = 0; i < 9; i++) np_[i] = (const float*)d_in[13 + i];

  float* v_out = (float*)d_out;
  float* e_out = (float*)d_out + (size_t)N * C;

  // workspace carve (~92 MB total)
  char* wsp = (char*)d_ws;
  size_t o = 0;
  auto carve = [&](size_t bytes) {
    void* p = wsp + o;
    o += (bytes + 255) & ~(size_t)255;
    return p;
  };
  __hip_bfloat16* h = (__hip_bfloat16*)carve((size_t)E * C * 2);
  int* counts = (int*)carve((size_t)E * 4);
  int* off = (int*)carve(((size_t)E + 1) * 4);
  int* cursor = (int*)carve((size_t)E * 4);
  int* bsums = (int*)carve(4096);
  int* csr_src = (int*)carve((size_t)LE * 4);
  int* csr_eid = (int*)carve((size_t)LE * 4);
  (void)ws_size;
  (void)n_in;
  (void)out_size;

  auto run_layer = [&](const float* x, const int* ei, int M, int nnz, const float* eattr,
                       const float** P, float* outp) {
    const int* src = ei;
    const int* dst = ei + nnz;
    hipMemsetAsync(counts, 0, (size_t)M * 4, stream);
    ln_relu_kernel<<<(M + 3) / 4, 256, 0, stream>>>(x, P[0], P[1], h, M);
    count_kernel<<<(nnz + 255) / 256, 256, 0, stream>>>(dst, counts, nnz);
    int nb = (M + 1023) / 1024;
    scan_block_sums<<<nb, 256, 0, stream>>>(counts, bsums, M);
    scan_serial<<<1, 1, 0, stream>>>(bsums, nb);
    scan_write<<<nb, 256, 0, stream>>>(counts, bsums, off, cursor, M, nnz);
    fill_kernel<<<(nnz + 255) / 256, 256, 0, stream>>>(src, dst, cursor, csr_src, csr_eid, nnz);
    int gblocks = (M + 15) / 16;
    if (eattr) {
      genconv_kernel<true><<<gblocks, 256, 0, stream>>>(x, h, off, csr_src, csr_eid, eattr,
                                                        P[2], P[3], P[4], P[5], P[6], P[7],
                                                        P[8], outp, M);
    } else {
      genconv_kernel<false><<<gblocks, 256, 0, stream>>>(x, h, off, csr_src, csr_eid, nullptr,
                                                         P[2], P[3], P[4], P[5], P[6], P[7],
                                                         P[8], outp, M);
    }
  };

  // edge layer over the line graph (no edge_attr), writes e_out
  run_layer(e_x, e_ei, E, LE, nullptr, ep, e_out);
  // node layer over node graph, edge_attr = e_out, writes v_out
  run_layer(v_x, v_ei, N, E, e_out, np_, v_out);
}

// Round 2
// 987.657 us; speedup vs baseline: 1.7914x; 1.7914x over previous
//
#include <hip/hip_runtime.h>
#include <hip/hip_bf16.h>

#define GEN_EPS 1e-7f

typedef __attribute__((ext_vector_type(8))) short short8;
typedef __attribute__((ext_vector_type(4))) float f32x4;

// ---------------------------------------------------------------------------
// h = relu(LayerNorm(x)) stored as bf16.  One wave per row (C=128, 2 ch/lane).
// ---------------------------------------------------------------------------
__global__ void ln_relu_kernel(const float* __restrict__ x, const float* __restrict__ g,
                               const float* __restrict__ b, __hip_bfloat16* __restrict__ h,
                               int M) {
  int lane = threadIdx.x & 63;
  int r = blockIdx.x * 4 + (threadIdx.x >> 6);
  if (r >= M) return;
  float2 v = ((const float2*)(x + (size_t)r * 128))[lane];
  float s = v.x + v.y;
#pragma unroll
  for (int o = 32; o; o >>= 1) s += __shfl_xor(s, o);
  float m = s * (1.0f / 128.0f);
  float dx = v.x - m, dy = v.y - m;
  float q = dx * dx + dy * dy;
#pragma unroll
  for (int o = 32; o; o >>= 1) q += __shfl_xor(q, o);
  float rstd = rsqrtf(q * (1.0f / 128.0f) + 1e-5f);
  float2 gv = ((const float2*)g)[lane], bv = ((const float2*)b)[lane];
  float2 hv;
  hv.x = fmaxf(fmaf(dx * rstd, gv.x, bv.x), 0.0f);
  hv.y = fmaxf(fmaf(dy * rstd, gv.y, bv.y), 0.0f);
  ((__hip_bfloat162*)(h + (size_t)r * 128))[lane] = __float22bfloat162_rn(hv);
}

// ---------------------------------------------------------------------------
// Weight pack: WT[c][k] = bf16(W[k][Cc-wide row, col c]); contiguous in k.
// ---------------------------------------------------------------------------
__global__ void wprep_kernel(const float* __restrict__ W, short* __restrict__ WT,
                             int R, int Cc) {
  int c = blockIdx.x;
  for (int k = threadIdx.x; k < R; k += blockDim.x) {
    __hip_bfloat16 bv = __float2bfloat16(W[(size_t)k * Cc + c]);
    WT[(size_t)c * R + k] = *(short*)&bv;
  }
}

// ---------------------------------------------------------------------------
// CSR construction: count -> scan -> fill
// ---------------------------------------------------------------------------
__global__ void count_kernel(const int* __restrict__ dst, int* __restrict__ counts, int nnz) {
  int i = blockIdx.x * blockDim.x + threadIdx.x;
  if (i < nnz) atomicAdd(&counts[dst[i]], 1);
}

__global__ void scan_block_sums(const int* __restrict__ counts, int* __restrict__ bsums, int M) {
  __shared__ int sm[256];
  int t = threadIdx.x;
  int base = blockIdx.x * 1024 + t * 4;
  int s = 0;
#pragma unroll
  for (int i = 0; i < 4; i++) {
    int idx = base + i;
    if (idx < M) s += counts[idx];
  }
  sm[t] = s;
  __syncthreads();
  for (int o = 128; o; o >>= 1) {
    if (t < o) sm[t] += sm[t + o];
    __syncthreads();
  }
  if (t == 0) bsums[blockIdx.x] = sm[0];
}

__global__ void scan_serial(int* bsums, int nb) {
  int acc = 0;
  for (int i = 0; i < nb; i++) {
    int v = bsums[i];
    bsums[i] = acc;
    acc += v;
  }
}

__global__ void scan_write(const int* __restrict__ counts, const int* __restrict__ bsums,
                           int* __restrict__ off, int* __restrict__ cursor, int M, int nnz) {
  __shared__ int sm[256];
  int t = threadIdx.x;
  int base = blockIdx.x * 1024 + t * 4;
  int c[4];
  int s = 0;
#pragma unroll
  for (int i = 0; i < 4; i++) {
    int idx = base + i;
    c[i] = (idx < M) ? counts[idx] : 0;
    s += c[i];
  }
  sm[t] = s;
  __syncthreads();
  for (int o = 1; o < 256; o <<= 1) {
    int v = (t >= o) ? sm[t - o] : 0;
    __syncthreads();
    sm[t] += v;
    __syncthreads();
  }
  int p = bsums[blockIdx.x] + sm[t] - s;
#pragma unroll
  for (int i = 0; i < 4; i++) {
    int idx = base + i;
    if (idx < M) {
      off[idx] = p;
      cursor[idx] = p;
      p += c[i];
    }
  }
  if (blockIdx.x == 0 && t == 0) off[M] = nnz;
}

__global__ void fill_kernel(const int* __restrict__ src, const int* __restrict__ dst,
                            int* __restrict__ cursor, int* __restrict__ csr_src,
                            int* __restrict__ csr_eid, int nnz) {
  int i = blockIdx.x * blockDim.x + threadIdx.x;
  if (i >= nnz) return;
  int d = dst[i];
  int p = atomicAdd(&cursor[d], 1);
  csr_src[p] = src[i];
  csr_eid[p] = i;
}

// ---------------------------------------------------------------------------
// Fused GENConv, 64 rows / 4 waves per block, MFMA MLP.
//   phase 1: softmax aggregation -> y (bf16 in LDS, stride 136)
//   GEMM1  : hid = y @ W1T^T + b1   (MFMA, C in regs)
//   LN+relu: in-register stats (shfl within 16-lane group) -> hid bf16 in LDS
//   GEMM2  : out = hid @ W2T^T + b2 + x  (res+)
// ---------------------------------------------------------------------------
template <bool HAS_EATTR>
__global__ __launch_bounds__(256) void genconv_mfma_kernel(
    const float* __restrict__ x, const __hip_bfloat16* __restrict__ h,
    const int* __restrict__ off, const int* __restrict__ csr_src,
    const int* __restrict__ csr_eid, const float* __restrict__ eattr,
    const float* __restrict__ tptr, const short* __restrict__ W1T,
    const float* __restrict__ b1, const float* __restrict__ lng,
    const float* __restrict__ lnb, const short* __restrict__ W2T,
    const float* __restrict__ b2, float* __restrict__ out, int M) {
  __shared__ short smem[64 * 264];  // aliased: Y (stride 136) then H (stride 264)
  const int tid = threadIdx.x, lane = tid & 63, wv = tid >> 6;
  const int row0 = blockIdx.x * 64;
  const float t = tptr[0];

  // ---- phase 1: aggregation, wave per row, 2 channels/lane ----
  for (int rr = wv; rr < 64; rr += 4) {
    int r = row0 + rr;
    if (r >= M) {
      ((uint*)&smem[rr * 136])[lane] = 0u;
      continue;
    }
    float2 hv = __bfloat1622float2(((const __hip_bfloat162*)(h + (size_t)r * 128))[lane]);
    int e0 = off[r], e1 = off[r + 1];
    float d0 = 0.0f, d1 = 0.0f, a0 = 0.0f, a1 = 0.0f;
#pragma unroll 2
    for (int e = e0; e < e1; e++) {
      int sidx = csr_src[e];
      float2 mv = __bfloat1622float2(((const __hip_bfloat162*)(h + (size_t)sidx * 128))[lane]);
      if (HAS_EATTR) {
        int id = csr_eid[e];
        float2 ea = ((const float2*)(eattr + (size_t)id * 128))[lane];
        mv.x += ea.x;
        mv.y += ea.y;
      }
      float m0 = fmaxf(mv.x, 0.0f) + GEN_EPS;
      float m1 = fmaxf(mv.y, 0.0f) + GEN_EPS;
      float al0 = __expf(m0 * t), al1 = __expf(m1 * t);
      d0 += al0;
      d1 += al1;
      a0 = fmaf(al0, m0, a0);
      a1 = fmaf(al1, m1, a1);
    }
    float2 yv;
    yv.x = (e1 > e0 ? a0 / d0 : 0.0f) + hv.x;
    yv.y = (e1 > e0 ? a1 / d1 : 0.0f) + hv.y;
    __hip_bfloat162 yb = __float22bfloat162_rn(yv);
    ((uint*)&smem[rr * 136])[lane] = *(uint*)&yb;
  }
  __syncthreads();

  const int rA = lane & 15;          // A row / B col / C col index
  const int kA = (lane >> 4) * 8;    // k-chunk base within 32
  const int jrow = (lane >> 4) * 4;  // C row base

  // ---- GEMM1: A frags from Y, B frags from W1T (global, L2-hot) ----
  short8 A1[4];
#pragma unroll
  for (int kc = 0; kc < 4; kc++)
    A1[kc] = *(const short8*)&smem[(wv * 16 + rA) * 136 + kc * 32 + kA];
  __syncthreads();  // Y dead; H region may now be written

  f32x4 C1[16];
#pragma unroll
  for (int ct = 0; ct < 16; ct++) C1[ct] = (f32x4)0.0f;
#pragma unroll
  for (int ct = 0; ct < 16; ct++) {
#pragma unroll
    for (int kc = 0; kc < 4; kc++) {
      short8 B = *(const short8*)&W1T[(size_t)(ct * 16 + rA) * 128 + kc * 32 + kA];
      C1[ct] = __builtin_amdgcn_mfma_f32_16x16x32_bf16(A1[kc], B, C1[ct], 0, 0, 0);
    }
  }

  // ---- + b1, in-register LN stats over 256 cols ----
#pragma unroll
  for (int ct = 0; ct < 16; ct++) {
    float bb = b1[ct * 16 + rA];
#pragma unroll
    for (int j = 0; j < 4; j++) C1[ct][j] += bb;
  }
  float s0 = 0, s1 = 0, s2 = 0, s3 = 0;
#pragma unroll
  for (int ct = 0; ct < 16; ct++) {
    s0 += C1[ct][0];
    s1 += C1[ct][1];
    s2 += C1[ct][2];
    s3 += C1[ct][3];
  }
#pragma unroll
  for (int o = 1; o < 16; o <<= 1) {
    s0 += __shfl_xor(s0, o);
    s1 += __shfl_xor(s1, o);
    s2 += __shfl_xor(s2, o);
    s3 += __shfl_xor(s3, o);
  }
  float m0 = s0 * (1.0f / 256.0f), m1 = s1 * (1.0f / 256.0f);
  float m2 = s2 * (1.0f / 256.0f), m3 = s3 * (1.0f / 256.0f);
  float q0 = 0, q1 = 0, q2 = 0, q3 = 0;
#pragma unroll
  for (int ct = 0; ct < 16; ct++) {
    float d;
    d = C1[ct][0] - m0; q0 = fmaf(d, d, q0);
    d = C1[ct][1] - m1; q1 = fmaf(d, d, q1);
    d = C1[ct][2] - m2; q2 = fmaf(d, d, q2);
    d = C1[ct][3] - m3; q3 = fmaf(d, d, q3);
  }
#pragma unroll
  for (int o = 1; o < 16; o <<= 1) {
    q0 += __shfl_xor(q0, o);
    q1 += __shfl_xor(q1, o);
    q2 += __shfl_xor(q2, o);
    q3 += __shfl_xor(q3, o);
  }
  float r0 = rsqrtf(q0 * (1.0f / 256.0f) + 1e-5f);
  float r1 = rsqrtf(q1 * (1.0f / 256.0f) + 1e-5f);
  float r2 = rsqrtf(q2 * (1.0f / 256.0f) + 1e-5f);
  float r3 = rsqrtf(q3 * (1.0f / 256.0f) + 1e-5f);

  // ---- normalize + relu -> H (bf16, stride 264) ----
#pragma unroll
  for (int ct = 0; ct < 16; ct++) {
    int col = ct * 16 + rA;
    float g = lng[col], bb = lnb[col];
    float v;
    __hip_bfloat16 bv;
    v = fmaxf(fmaf((C1[ct][0] - m0) * r0, g, bb), 0.0f);
    bv = __float2bfloat16(v);
    smem[(wv * 16 + jrow + 0) * 264 + col] = *(short*)&bv;
    v = fmaxf(fmaf((C1[ct][1] - m1) * r1, g, bb), 0.0f);
    bv = __float2bfloat16(v);
    smem[(wv * 16 + jrow + 1) * 264 + col] = *(short*)&bv;
    v = fmaxf(fmaf((C1[ct][2] - m2) * r2, g, bb), 0.0f);
    bv = __float2bfloat16(v);
    smem[(wv * 16 + jrow + 2) * 264 + col] = *(short*)&bv;
    v = fmaxf(fmaf((C1[ct][3] - m3) * r3, g, bb), 0.0f);
    bv = __float2bfloat16(v);
    smem[(wv * 16 + jrow + 3) * 264 + col] = *(short*)&bv;
  }
  __syncthreads();

  // ---- GEMM2: A frags from H, B frags from W2T ----
  short8 A2[8];
#pragma unroll
  for (int kc = 0; kc < 8; kc++)
    A2[kc] = *(const short8*)&smem[(wv * 16 + rA) * 264 + kc * 32 + kA];
  f32x4 C2[8];
#pragma unroll
  for (int ct = 0; ct < 8; ct++) C2[ct] = (f32x4)0.0f;
#pragma unroll
  for (int ct = 0; ct < 8; ct++) {
#pragma unroll
    for (int kc = 0; kc < 8; kc++) {
      short8 B = *(const short8*)&W2T[(size_t)(ct * 16 + rA) * 256 + kc * 32 + kA];
      C2[ct] = __builtin_amdgcn_mfma_f32_16x16x32_bf16(A2[kc], B, C2[ct], 0, 0, 0);
    }
  }

  // ---- epilogue: + b2 + x, store ----
#pragma unroll
  for (int ct = 0; ct < 8; ct++) {
    int col = ct * 16 + rA;
    float bb = b2[col];
#pragma unroll
    for (int j = 0; j < 4; j++) {
      int row = row0 + wv * 16 + jrow + j;
      if (row < M) {
        size_t idx = (size_t)row * 128 + col;
        out[idx] = C2[ct][j] + bb + x[idx];
      }
    }
  }
}

// ---------------------------------------------------------------------------
extern "C" void kernel_launch(void* const* d_in, const int* in_sizes, int n_in,
                              void* d_out, int out_size, void* d_ws, size_t ws_size,
                              hipStream_t stream) {
  const int C = 128;
  const float* v_x = (const float*)d_in[0];
  const float* e_x = (const float*)d_in[1];
  const int* v_ei = (const int*)d_in[2];
  const int* e_ei = (const int*)d_in[3];
  const int N = in_sizes[0] / C;
  const int E = in_sizes[1] / C;
  const int LE = in_sizes[3] / 2;

  const float* ep[9];
  const float* np_[9];
  for (int i = 0; i < 9; i++) ep[i] = (const float*)d_in[4 + i];
  for (int i = 0; i < 9; i++) np_[i] = (const float*)d_in[13 + i];

  float* v_out = (float*)d_out;
  float* e_out = (float*)d_out + (size_t)N * C;

  char* wsp = (char*)d_ws;
  size_t o = 0;
  auto carve = [&](size_t bytes) {
    void* p = wsp + o;
    o += (bytes + 255) & ~(size_t)255;
    return p;
  };
  __hip_bfloat16* h = (__hip_bfloat16*)carve((size_t)E * C * 2);
  int* counts = (int*)carve((size_t)E * 4);
  int* off = (int*)carve(((size_t)E + 1) * 4);
  int* cursor = (int*)carve((size_t)E * 4);
  int* bsums = (int*)carve(4096);
  int* csr_src = (int*)carve((size_t)LE * 4);
  int* csr_eid = (int*)carve((size_t)LE * 4);
  short* eW1T = (short*)carve((size_t)256 * 128 * 2);
  short* eW2T = (short*)carve((size_t)128 * 256 * 2);
  short* nW1T = (short*)carve((size_t)256 * 128 * 2);
  short* nW2T = (short*)carve((size_t)128 * 256 * 2);
  (void)ws_size;
  (void)n_in;
  (void)out_size;

  auto run_layer = [&](const float* x, const int* ei, int M, int nnz, const float* eattr,
                       const float** P, short* W1T, short* W2T, float* outp) {
    const int* src = ei;
    const int* dst = ei + nnz;
    hipMemsetAsync(counts, 0, (size_t)M * 4, stream);
    wprep_kernel<<<256, 128, 0, stream>>>(P[3], W1T, 128, 256);
    wprep_kernel<<<128, 256, 0, stream>>>(P[7], W2T, 256, 128);
    ln_relu_kernel<<<(M + 3) / 4, 256, 0, stream>>>(x, P[0], P[1], h, M);
    count_kernel<<<(nnz + 255) / 256, 256, 0, stream>>>(dst, counts, nnz);
    int nb = (M + 1023) / 1024;
    scan_block_sums<<<nb, 256, 0, stream>>>(counts, bsums, M);
    scan_serial<<<1, 1, 0, stream>>>(bsums, nb);
    scan_write<<<nb, 256, 0, stream>>>(counts, bsums, off, cursor, M, nnz);
    fill_kernel<<<(nnz + 255) / 256, 256, 0, stream>>>(src, dst, cursor, csr_src, csr_eid, nnz);
    int gblocks = (M + 63) / 64;
    if (eattr) {
      genconv_mfma_kernel<true><<<gblocks, 256, 0, stream>>>(
          x, h, off, csr_src, csr_eid, eattr, P[2], W1T, P[4], P[5], P[6], W2T, P[8], outp, M);
    } else {
      genconv_mfma_kernel<false><<<gblocks, 256, 0, stream>>>(
          x, h, off, csr_src, csr_eid, nullptr, P[2], W1T, P[4], P[5], P[6], W2T, P[8], outp, M);
    }
  };

  run_layer(e_x, e_ei, E, LE, nullptr, ep, eW1T, eW2T, e_out);
  run_layer(v_x, v_ei, N, E, e_out, np_, nW1T, nW2T, v_out);
}

// Round 3
// 843.670 us; speedup vs baseline: 2.0971x; 1.1707x over previous
//
#include <hip/hip_runtime.h>
#include <hip/hip_bf16.h>

#define GEN_EPS 1e-7f

typedef __attribute__((ext_vector_type(8))) short short8;
typedef __attribute__((ext_vector_type(4))) float f32x4;

// ---------------------------------------------------------------------------
// h = relu(LayerNorm(x)) stored as bf16.  One wave per row (C=128, 2 ch/lane).
// ---------------------------------------------------------------------------
__global__ void ln_relu_kernel(const float* __restrict__ x, const float* __restrict__ g,
                               const float* __restrict__ b, __hip_bfloat16* __restrict__ h,
                               int M) {
  int lane = threadIdx.x & 63;
  int r = blockIdx.x * 4 + (threadIdx.x >> 6);
  if (r >= M) return;
  float2 v = ((const float2*)(x + (size_t)r * 128))[lane];
  float s = v.x + v.y;
#pragma unroll
  for (int o = 32; o; o >>= 1) s += __shfl_xor(s, o);
  float m = s * (1.0f / 128.0f);
  float dx = v.x - m, dy = v.y - m;
  float q = dx * dx + dy * dy;
#pragma unroll
  for (int o = 32; o; o >>= 1) q += __shfl_xor(q, o);
  float rstd = rsqrtf(q * (1.0f / 128.0f) + 1e-5f);
  float2 gv = ((const float2*)g)[lane], bv = ((const float2*)b)[lane];
  float2 hv;
  hv.x = fmaxf(fmaf(dx * rstd, gv.x, bv.x), 0.0f);
  hv.y = fmaxf(fmaf(dy * rstd, gv.y, bv.y), 0.0f);
  ((__hip_bfloat162*)(h + (size_t)r * 128))[lane] = __float22bfloat162_rn(hv);
}

// ---------------------------------------------------------------------------
// Weight pack: WT[c][k] = bf16(W[k][c]); contiguous in k.
// ---------------------------------------------------------------------------
__global__ void wprep_kernel(const float* __restrict__ W, short* __restrict__ WT,
                             int R, int Cc) {
  int c = blockIdx.x;
  for (int k = threadIdx.x; k < R; k += blockDim.x) {
    __hip_bfloat16 bv = __float2bfloat16(W[(size_t)k * Cc + c]);
    WT[(size_t)c * R + k] = *(short*)&bv;
  }
}

// ---------------------------------------------------------------------------
// CSR construction: count -> scan -> fill
// ---------------------------------------------------------------------------
__global__ void count_kernel(const int* __restrict__ dst, int* __restrict__ counts, int nnz) {
  int i = blockIdx.x * blockDim.x + threadIdx.x;
  if (i < nnz) atomicAdd(&counts[dst[i]], 1);
}

__global__ void scan_block_sums(const int* __restrict__ counts, int* __restrict__ bsums, int M) {
  __shared__ int sm[256];
  int t = threadIdx.x;
  int base = blockIdx.x * 1024 + t * 4;
  int s = 0;
#pragma unroll
  for (int i = 0; i < 4; i++) {
    int idx = base + i;
    if (idx < M) s += counts[idx];
  }
  sm[t] = s;
  __syncthreads();
  for (int o = 128; o; o >>= 1) {
    if (t < o) sm[t] += sm[t + o];
    __syncthreads();
  }
  if (t == 0) bsums[blockIdx.x] = sm[0];
}

// one-block exclusive scan over up to 512 block sums
__global__ void scan_bsums(int* bsums, int nb) {
  __shared__ int sm[512];
  int t = threadIdx.x;
  int v = (t < nb) ? bsums[t] : 0;
  sm[t] = v;
  __syncthreads();
  for (int o = 1; o < 512; o <<= 1) {
    int u = (t >= o) ? sm[t - o] : 0;
    __syncthreads();
    sm[t] += u;
    __syncthreads();
  }
  if (t < nb) bsums[t] = sm[t] - v;  // exclusive
}

__global__ void scan_write(const int* __restrict__ counts, const int* __restrict__ bsums,
                           int* __restrict__ off, int* __restrict__ cursor, int M, int nnz) {
  __shared__ int sm[256];
  int t = threadIdx.x;
  int base = blockIdx.x * 1024 + t * 4;
  int c[4];
  int s = 0;
#pragma unroll
  for (int i = 0; i < 4; i++) {
    int idx = base + i;
    c[i] = (idx < M) ? counts[idx] : 0;
    s += c[i];
  }
  sm[t] = s;
  __syncthreads();
  for (int o = 1; o < 256; o <<= 1) {
    int v = (t >= o) ? sm[t - o] : 0;
    __syncthreads();
    sm[t] += v;
    __syncthreads();
  }
  int p = bsums[blockIdx.x] + sm[t] - s;
#pragma unroll
  for (int i = 0; i < 4; i++) {
    int idx = base + i;
    if (idx < M) {
      off[idx] = p;
      cursor[idx] = p;
      p += c[i];
    }
  }
  if (blockIdx.x == 0 && t == 0) off[M] = nnz;
}

__global__ void fill_kernel(const int* __restrict__ src, const int* __restrict__ dst,
                            int* __restrict__ cursor, int* __restrict__ csr_src,
                            int* __restrict__ csr_eid, int nnz) {
  int i = blockIdx.x * blockDim.x + threadIdx.x;
  if (i >= nnz) return;
  int d = dst[i];
  int p = atomicAdd(&cursor[d], 1);
  csr_src[p] = src[i];
  csr_eid[p] = i;
}

// ---------------------------------------------------------------------------
// Softmax aggregation, one wave per destination row, 2 channels per lane.
// Writes y = aggr + h fp32 into the output region (in-place MLP follows).
// Software-prefetch of the next edge's indices overlaps gather latency.
// ---------------------------------------------------------------------------
template <bool HAS_EATTR>
__global__ __launch_bounds__(256) void aggregate_kernel(
    const __hip_bfloat16* __restrict__ h, const int* __restrict__ off,
    const int* __restrict__ csr_src, const int* __restrict__ csr_eid,
    const float* __restrict__ eattr, const float* __restrict__ tptr,
    float* __restrict__ y, int M) {
  int lane = threadIdx.x & 63;
  int r = blockIdx.x * 4 + (threadIdx.x >> 6);
  if (r >= M) return;
  const float t = tptr[0];
  float2 hv = __bfloat1622float2(((const __hip_bfloat162*)(h + (size_t)r * 128))[lane]);
  int e0 = off[r], e1 = off[r + 1];
  float d0 = 0.0f, d1 = 0.0f, a0 = 0.0f, a1 = 0.0f;
  int sN = 0, idN = 0;
  if (e0 < e1) {
    sN = csr_src[e0];
    if (HAS_EATTR) idN = csr_eid[e0];
  }
  for (int e = e0; e < e1; e++) {
    int s = sN, id = idN;
    if (e + 1 < e1) {
      sN = csr_src[e + 1];
      if (HAS_EATTR) idN = csr_eid[e + 1];
    }
    float2 mv = __bfloat1622float2(((const __hip_bfloat162*)(h + (size_t)s * 128))[lane]);
    if (HAS_EATTR) {
      float2 ea = ((const float2*)(eattr + (size_t)id * 128))[lane];
      mv.x += ea.x;
      mv.y += ea.y;
    }
    float m0 = fmaxf(mv.x, 0.0f) + GEN_EPS;
    float m1 = fmaxf(mv.y, 0.0f) + GEN_EPS;
    float al0 = __expf(m0 * t), al1 = __expf(m1 * t);
    d0 += al0;
    d1 += al1;
    a0 = fmaf(al0, m0, a0);
    a1 = fmaf(al1, m1, a1);
  }
  float2 yv;
  yv.x = (e1 > e0 ? a0 / d0 : 0.0f) + hv.x;
  yv.y = (e1 > e0 ? a1 / d1 : 0.0f) + hv.y;
  ((float2*)(y + (size_t)r * 128))[lane] = yv;
}

// ---------------------------------------------------------------------------
// MLP over rows, in place on y (fp32, 128 cols): 64 rows / 4 waves per block.
//   GEMM1 : hid = y @ W1T^T + b1  (MFMA bf16, C in regs)
//   LN+relu in-register (shfl within 16-lane groups) -> H bf16 in LDS
//   GEMM2 : y = hid @ W2T^T + b2 + x   (res+ residual)
// Each wave touches only its own 16-row stripe of y -> in-place is safe.
// ---------------------------------------------------------------------------
__global__ __launch_bounds__(256) void mlp_kernel(
    const float* __restrict__ x, float* __restrict__ y, const short* __restrict__ W1T,
    const float* __restrict__ b1, const float* __restrict__ lng,
    const float* __restrict__ lnb, const short* __restrict__ W2T,
    const float* __restrict__ b2, int M) {
  __shared__ short Hs[64 * 264];
  const int tid = threadIdx.x, lane = tid & 63, wv = tid >> 6;
  const int row0 = blockIdx.x * 64;
  const int rA = lane & 15;          // A row / B col / C col index
  const int kA = (lane >> 4) * 8;    // k-chunk base within 32
  const int jrow = (lane >> 4) * 4;  // C row base
  const int arow = row0 + wv * 16 + rA;
  const bool rok = arow < M;

  // ---- A1 frags straight from global y (fp32 -> bf16) ----
  short8 A1[4];
  if (rok) {
    const float4* yr = (const float4*)(y + (size_t)arow * 128);
#pragma unroll
    for (int kc = 0; kc < 4; kc++) {
      float4 f0 = yr[kc * 8 + (lane >> 4) * 2];
      float4 f1 = yr[kc * 8 + (lane >> 4) * 2 + 1];
      short8 a;
      __hip_bfloat16 bv;
      bv = __float2bfloat16(f0.x); a[0] = *(short*)&bv;
      bv = __float2bfloat16(f0.y); a[1] = *(short*)&bv;
      bv = __float2bfloat16(f0.z); a[2] = *(short*)&bv;
      bv = __float2bfloat16(f0.w); a[3] = *(short*)&bv;
      bv = __float2bfloat16(f1.x); a[4] = *(short*)&bv;
      bv = __float2bfloat16(f1.y); a[5] = *(short*)&bv;
      bv = __float2bfloat16(f1.z); a[6] = *(short*)&bv;
      bv = __float2bfloat16(f1.w); a[7] = *(short*)&bv;
      A1[kc] = a;
    }
  } else {
#pragma unroll
    for (int kc = 0; kc < 4; kc++) A1[kc] = (short8)0;
  }

  // ---- GEMM1 ----
  f32x4 C1[16];
#pragma unroll
  for (int ct = 0; ct < 16; ct++) C1[ct] = (f32x4)0.0f;
#pragma unroll
  for (int ct = 0; ct < 16; ct++) {
#pragma unroll
    for (int kc = 0; kc < 4; kc++) {
      short8 B = *(const short8*)&W1T[(size_t)(ct * 16 + rA) * 128 + kc * 32 + kA];
      C1[ct] = __builtin_amdgcn_mfma_f32_16x16x32_bf16(A1[kc], B, C1[ct], 0, 0, 0);
    }
  }

  // ---- + b1, in-register LN stats over 256 cols ----
#pragma unroll
  for (int ct = 0; ct < 16; ct++) {
    float bb = b1[ct * 16 + rA];
#pragma unroll
    for (int j = 0; j < 4; j++) C1[ct][j] += bb;
  }
  float s0 = 0, s1 = 0, s2 = 0, s3 = 0;
#pragma unroll
  for (int ct = 0; ct < 16; ct++) {
    s0 += C1[ct][0];
    s1 += C1[ct][1];
    s2 += C1[ct][2];
    s3 += C1[ct][3];
  }
#pragma unroll
  for (int o = 1; o < 16; o <<= 1) {
    s0 += __shfl_xor(s0, o);
    s1 += __shfl_xor(s1, o);
    s2 += __shfl_xor(s2, o);
    s3 += __shfl_xor(s3, o);
  }
  float m0 = s0 * (1.0f / 256.0f), m1 = s1 * (1.0f / 256.0f);
  float m2 = s2 * (1.0f / 256.0f), m3 = s3 * (1.0f / 256.0f);
  float q0 = 0, q1 = 0, q2 = 0, q3 = 0;
#pragma unroll
  for (int ct = 0; ct < 16; ct++) {
    float d;
    d = C1[ct][0] - m0; q0 = fmaf(d, d, q0);
    d = C1[ct][1] - m1; q1 = fmaf(d, d, q1);
    d = C1[ct][2] - m2; q2 = fmaf(d, d, q2);
    d = C1[ct][3] - m3; q3 = fmaf(d, d, q3);
  }
#pragma unroll
  for (int o = 1; o < 16; o <<= 1) {
    q0 += __shfl_xor(q0, o);
    q1 += __shfl_xor(q1, o);
    q2 += __shfl_xor(q2, o);
    q3 += __shfl_xor(q3, o);
  }
  float r0 = rsqrtf(q0 * (1.0f / 256.0f) + 1e-5f);
  float r1 = rsqrtf(q1 * (1.0f / 256.0f) + 1e-5f);
  float r2 = rsqrtf(q2 * (1.0f / 256.0f) + 1e-5f);
  float r3 = rsqrtf(q3 * (1.0f / 256.0f) + 1e-5f);

  // ---- normalize + relu -> H (bf16, stride 264) ----
#pragma unroll
  for (int ct = 0; ct < 16; ct++) {
    int col = ct * 16 + rA;
    float g = lng[col], bb = lnb[col];
    float v;
    __hip_bfloat16 bv;
    v = fmaxf(fmaf((C1[ct][0] - m0) * r0, g, bb), 0.0f);
    bv = __float2bfloat16(v);
    Hs[(wv * 16 + jrow + 0) * 264 + col] = *(short*)&bv;
    v = fmaxf(fmaf((C1[ct][1] - m1) * r1, g, bb), 0.0f);
    bv = __float2bfloat16(v);
    Hs[(wv * 16 + jrow + 1) * 264 + col] = *(short*)&bv;
    v = fmaxf(fmaf((C1[ct][2] - m2) * r2, g, bb), 0.0f);
    bv = __float2bfloat16(v);
    Hs[(wv * 16 + jrow + 2) * 264 + col] = *(short*)&bv;
    v = fmaxf(fmaf((C1[ct][3] - m3) * r3, g, bb), 0.0f);
    bv = __float2bfloat16(v);
    Hs[(wv * 16 + jrow + 3) * 264 + col] = *(short*)&bv;
  }
  __syncthreads();

  // ---- GEMM2: A frags from H ----
  short8 A2[8];
#pragma unroll
  for (int kc = 0; kc < 8; kc++)
    A2[kc] = *(const short8*)&Hs[(wv * 16 + rA) * 264 + kc * 32 + kA];
  f32x4 C2[8];
#pragma unroll
  for (int ct = 0; ct < 8; ct++) C2[ct] = (f32x4)0.0f;
#pragma unroll
  for (int ct = 0; ct < 8; ct++) {
#pragma unroll
    for (int kc = 0; kc < 8; kc++) {
      short8 B = *(const short8*)&W2T[(size_t)(ct * 16 + rA) * 256 + kc * 32 + kA];
      C2[ct] = __builtin_amdgcn_mfma_f32_16x16x32_bf16(A2[kc], B, C2[ct], 0, 0, 0);
    }
  }

  // ---- epilogue: y = C2 + b2 + x (res+) ----
#pragma unroll
  for (int ct = 0; ct < 8; ct++) {
    int col = ct * 16 + rA;
    float bb = b2[col];
#pragma unroll
    for (int j = 0; j < 4; j++) {
      int row = row0 + wv * 16 + jrow + j;
      if (row < M) {
        size_t idx = (size_t)row * 128 + col;
        y[idx] = C2[ct][j] + bb + x[idx];
      }
    }
  }
}

// ---------------------------------------------------------------------------
extern "C" void kernel_launch(void* const* d_in, const int* in_sizes, int n_in,
                              void* d_out, int out_size, void* d_ws, size_t ws_size,
                              hipStream_t stream) {
  const int C = 128;
  const float* v_x = (const float*)d_in[0];
  const float* e_x = (const float*)d_in[1];
  const int* v_ei = (const int*)d_in[2];
  const int* e_ei = (const int*)d_in[3];
  const int N = in_sizes[0] / C;
  const int E = in_sizes[1] / C;
  const int LE = in_sizes[3] / 2;

  const float* ep[9];
  const float* np_[9];
  for (int i = 0; i < 9; i++) ep[i] = (const float*)d_in[4 + i];
  for (int i = 0; i < 9; i++) np_[i] = (const float*)d_in[13 + i];

  float* v_out = (float*)d_out;
  float* e_out = (float*)d_out + (size_t)N * C;

  char* wsp = (char*)d_ws;
  size_t o = 0;
  auto carve = [&](size_t bytes) {
    void* p = wsp + o;
    o += (bytes + 255) & ~(size_t)255;
    return p;
  };
  __hip_bfloat16* h = (__hip_bfloat16*)carve((size_t)E * C * 2);
  int* counts = (int*)carve((size_t)E * 4);
  int* off = (int*)carve(((size_t)E + 1) * 4);
  int* cursor = (int*)carve((size_t)E * 4);
  int* bsums = (int*)carve(4096);
  int* csr_src = (int*)carve((size_t)LE * 4);
  int* csr_eid = (int*)carve((size_t)LE * 4);
  short* eW1T = (short*)carve((size_t)256 * 128 * 2);
  short* eW2T = (short*)carve((size_t)128 * 256 * 2);
  short* nW1T = (short*)carve((size_t)256 * 128 * 2);
  short* nW2T = (short*)carve((size_t)128 * 256 * 2);
  (void)ws_size;
  (void)n_in;
  (void)out_size;

  auto run_layer = [&](const float* x, const int* ei, int M, int nnz, const float* eattr,
                       const float** P, short* W1T, short* W2T, float* outp) {
    const int* src = ei;
    const int* dst = ei + nnz;
    hipMemsetAsync(counts, 0, (size_t)M * 4, stream);
    wprep_kernel<<<256, 128, 0, stream>>>(P[3], W1T, 128, 256);
    wprep_kernel<<<128, 256, 0, stream>>>(P[7], W2T, 256, 128);
    ln_relu_kernel<<<(M + 3) / 4, 256, 0, stream>>>(x, P[0], P[1], h, M);
    count_kernel<<<(nnz + 255) / 256, 256, 0, stream>>>(dst, counts, nnz);
    int nb = (M + 1023) / 1024;
    scan_block_sums<<<nb, 256, 0, stream>>>(counts, bsums, M);
    scan_bsums<<<1, 512, 0, stream>>>(bsums, nb);
    scan_write<<<nb, 256, 0, stream>>>(counts, bsums, off, cursor, M, nnz);
    fill_kernel<<<(nnz + 255) / 256, 256, 0, stream>>>(src, dst, cursor, csr_src, csr_eid, nnz);
    // aggregation writes y fp32 into outp; MLP then runs in place on outp
    if (eattr) {
      aggregate_kernel<true><<<(M + 3) / 4, 256, 0, stream>>>(h, off, csr_src, csr_eid,
                                                              eattr, P[2], outp, M);
    } else {
      aggregate_kernel<false><<<(M + 3) / 4, 256, 0, stream>>>(h, off, csr_src, csr_eid,
                                                               nullptr, P[2], outp, M);
    }
    mlp_kernel<<<(M + 63) / 64, 256, 0, stream>>>(x, outp, W1T, P[4], P[5], P[6], W2T,
                                                  P[8], M);
  };

  run_layer(e_x, e_ei, E, LE, nullptr, ep, eW1T, eW2T, e_out);
  run_layer(v_x, v_ei, N, E, e_out, np_, nW1T, nW2T, v_out);
}

// Round 4
// 578.496 us; speedup vs baseline: 3.0584x; 1.4584x over previous
//
#include <hip/hip_runtime.h>
#include <hip/hip_bf16.h>

#define GEN_EPS 1e-7f

typedef __attribute__((ext_vector_type(8))) short short8;
typedef __attribute__((ext_vector_type(4))) float f32x4;

// ---------------------------------------------------------------------------
// h = relu(LayerNorm(x)) stored as bf16.  One wave per row (C=128, 2 ch/lane).
// ---------------------------------------------------------------------------
__global__ void ln_relu_kernel(const float* __restrict__ x, const float* __restrict__ g,
                               const float* __restrict__ b, __hip_bfloat16* __restrict__ h,
                               int M) {
  int lane = threadIdx.x & 63;
  int r = blockIdx.x * 4 + (threadIdx.x >> 6);
  if (r >= M) return;
  float2 v = ((const float2*)(x + (size_t)r * 128))[lane];
  float s = v.x + v.y;
#pragma unroll
  for (int o = 32; o; o >>= 1) s += __shfl_xor(s, o);
  float m = s * (1.0f / 128.0f);
  float dx = v.x - m, dy = v.y - m;
  float q = dx * dx + dy * dy;
#pragma unroll
  for (int o = 32; o; o >>= 1) q += __shfl_xor(q, o);
  float rstd = rsqrtf(q * (1.0f / 128.0f) + 1e-5f);
  float2 gv = ((const float2*)g)[lane], bv = ((const float2*)b)[lane];
  float2 hv;
  hv.x = fmaxf(fmaf(dx * rstd, gv.x, bv.x), 0.0f);
  hv.y = fmaxf(fmaf(dy * rstd, gv.y, bv.y), 0.0f);
  ((__hip_bfloat162*)(h + (size_t)r * 128))[lane] = __float22bfloat162_rn(hv);
}

// ---------------------------------------------------------------------------
// Weight pack: WT[c][k] = bf16(W[k][c]); contiguous in k.
// ---------------------------------------------------------------------------
__global__ void wprep_kernel(const float* __restrict__ W, short* __restrict__ WT,
                             int R, int Cc) {
  int c = blockIdx.x;
  for (int k = threadIdx.x; k < R; k += blockDim.x) {
    __hip_bfloat16 bv = __float2bfloat16(W[(size_t)k * Cc + c]);
    WT[(size_t)c * R + k] = *(short*)&bv;
  }
}

// ---------------------------------------------------------------------------
// CSR construction: count -> scan -> fill
// ---------------------------------------------------------------------------
__global__ void count_kernel(const int* __restrict__ dst, int* __restrict__ counts, int nnz) {
  int i = blockIdx.x * blockDim.x + threadIdx.x;
  if (i < nnz) atomicAdd(&counts[dst[i]], 1);
}

__global__ void scan_block_sums(const int* __restrict__ counts, int* __restrict__ bsums, int M) {
  __shared__ int sm[256];
  int t = threadIdx.x;
  int base = blockIdx.x * 1024 + t * 4;
  int s = 0;
#pragma unroll
  for (int i = 0; i < 4; i++) {
    int idx = base + i;
    if (idx < M) s += counts[idx];
  }
  sm[t] = s;
  __syncthreads();
  for (int o = 128; o; o >>= 1) {
    if (t < o) sm[t] += sm[t + o];
    __syncthreads();
  }
  if (t == 0) bsums[blockIdx.x] = sm[0];
}

// one-block exclusive scan over up to 512 block sums
__global__ void scan_bsums(int* bsums, int nb) {
  __shared__ int sm[512];
  int t = threadIdx.x;
  int v = (t < nb) ? bsums[t] : 0;
  sm[t] = v;
  __syncthreads();
  for (int o = 1; o < 512; o <<= 1) {
    int u = (t >= o) ? sm[t - o] : 0;
    __syncthreads();
    sm[t] += u;
    __syncthreads();
  }
  if (t < nb) bsums[t] = sm[t] - v;  // exclusive
}

__global__ void scan_write(const int* __restrict__ counts, const int* __restrict__ bsums,
                           int* __restrict__ off, int* __restrict__ cursor, int M, int nnz) {
  __shared__ int sm[256];
  int t = threadIdx.x;
  int base = blockIdx.x * 1024 + t * 4;
  int c[4];
  int s = 0;
#pragma unroll
  for (int i = 0; i < 4; i++) {
    int idx = base + i;
    c[i] = (idx < M) ? counts[idx] : 0;
    s += c[i];
  }
  sm[t] = s;
  __syncthreads();
  for (int o = 1; o < 256; o <<= 1) {
    int v = (t >= o) ? sm[t - o] : 0;
    __syncthreads();
    sm[t] += v;
    __syncthreads();
  }
  int p = bsums[blockIdx.x] + sm[t] - s;
#pragma unroll
  for (int i = 0; i < 4; i++) {
    int idx = base + i;
    if (idx < M) {
      off[idx] = p;
      cursor[idx] = p;
      p += c[i];
    }
  }
  if (blockIdx.x == 0 && t == 0) off[M] = nnz;
}

__global__ void fill_kernel(const int* __restrict__ src, const int* __restrict__ dst,
                            int* __restrict__ cursor, int* __restrict__ csr_src,
                            int* __restrict__ csr_eid, int nnz) {
  int i = blockIdx.x * blockDim.x + threadIdx.x;
  if (i >= nnz) return;
  int d = dst[i];
  int p = atomicAdd(&cursor[d], 1);
  csr_src[p] = src[i];
  csr_eid[p] = i;
}

// ---------------------------------------------------------------------------
// Softmax aggregation, one wave per destination row, 2 channels per lane.
// Writes y = aggr + h fp32 into the output region (in-place MLP follows).
// ---------------------------------------------------------------------------
template <bool HAS_EATTR>
__global__ __launch_bounds__(256) void aggregate_kernel(
    const __hip_bfloat16* __restrict__ h, const int* __restrict__ off,
    const int* __restrict__ csr_src, const int* __restrict__ csr_eid,
    const float* __restrict__ eattr, const float* __restrict__ tptr,
    float* __restrict__ y, int M) {
  int lane = threadIdx.x & 63;
  int r = blockIdx.x * 4 + (threadIdx.x >> 6);
  if (r >= M) return;
  const float t = tptr[0];
  float2 hv = __bfloat1622float2(((const __hip_bfloat162*)(h + (size_t)r * 128))[lane]);
  int e0 = off[r], e1 = off[r + 1];
  float d0 = 0.0f, d1 = 0.0f, a0 = 0.0f, a1 = 0.0f;
  int sN = 0, idN = 0;
  if (e0 < e1) {
    sN = csr_src[e0];
    if (HAS_EATTR) idN = csr_eid[e0];
  }
  for (int e = e0; e < e1; e++) {
    int s = sN, id = idN;
    if (e + 1 < e1) {
      sN = csr_src[e + 1];
      if (HAS_EATTR) idN = csr_eid[e + 1];
    }
    float2 mv = __bfloat1622float2(((const __hip_bfloat162*)(h + (size_t)s * 128))[lane]);
    if (HAS_EATTR) {
      float2 ea = ((const float2*)(eattr + (size_t)id * 128))[lane];
      mv.x += ea.x;
      mv.y += ea.y;
    }
    float m0 = fmaxf(mv.x, 0.0f) + GEN_EPS;
    float m1 = fmaxf(mv.y, 0.0f) + GEN_EPS;
    float al0 = __expf(m0 * t), al1 = __expf(m1 * t);
    d0 += al0;
    d1 += al1;
    a0 = fmaf(al0, m0, a0);
    a1 = fmaf(al1, m1, a1);
  }
  float2 yv;
  yv.x = (e1 > e0 ? a0 / d0 : 0.0f) + hv.x;
  yv.y = (e1 > e0 ? a1 / d1 : 0.0f) + hv.y;
  ((float2*)(y + (size_t)r * 128))[lane] = yv;
}

// ---------------------------------------------------------------------------
// MLP over rows, in place on y (fp32, 128 cols): 64 rows / 4 waves per block.
// N-SPLIT across waves: wave w owns hidden cols [w*64, w*64+64) in GEMM1 and
// output cols [w*32, w*32+32) in GEMM2 -> B-frags are register-resident
// (16 frags each), loaded once per block. A-frags come from LDS.
//   stage y -> LDS bf16 -> GEMM1 -> LN (shfl + LDS atomics) -> H in LDS
//   -> GEMM2 -> C2 staged in LDS -> coalesced float4 epilogue (+b2 +x).
// ---------------------------------------------------------------------------
__global__ __launch_bounds__(256) void mlp_kernel(
    const float* __restrict__ x, float* __restrict__ y, const short* __restrict__ W1T,
    const float* __restrict__ b1, const float* __restrict__ lng,
    const float* __restrict__ lnb, const short* __restrict__ W2T,
    const float* __restrict__ b2, int M) {
  __shared__ char smem_raw[51712];
  short* yb = (short*)smem_raw;               // [64][136] bf16
  short* Hs = (short*)(smem_raw + 17408);     // [64][264] bf16
  float* stats = (float*)(smem_raw + 51200);  // [64][2]
  float* outst = (float*)smem_raw;            // [64][133] f32, aliases yb/Hs

  const int tid = threadIdx.x, lane = tid & 63, wv = tid >> 6;
  const int row0 = blockIdx.x * 64;
  const int rA = lane & 15;
  const int hi = lane >> 4;
  const int kA = hi * 8;
  const int jrow = hi * 4;

  if (tid < 128) stats[tid] = 0.0f;

  // ---- stage y -> yb (bf16), coalesced float4 ----
  {
    int r = tid >> 2;
    int c0 = (tid & 3) * 32;
    int gr = row0 + r;
    if (gr < M) {
      const float4* yr = (const float4*)(y + (size_t)gr * 128 + c0);
#pragma unroll
      for (int i = 0; i < 8; i++) {
        float4 f = yr[i];
        __hip_bfloat162 p0 = __float22bfloat162_rn({f.x, f.y});
        __hip_bfloat162 p1 = __float22bfloat162_rn({f.z, f.w});
        uint* dst = (uint*)(yb + r * 136 + c0 + i * 4);
        dst[0] = *(uint*)&p0;
        dst[1] = *(uint*)&p1;
      }
    } else {
#pragma unroll
      for (int i = 0; i < 8; i++) {
        uint* dst = (uint*)(yb + r * 136 + c0 + i * 4);
        dst[0] = 0u;
        dst[1] = 0u;
      }
    }
  }

  // ---- B1 frags + per-col params (register-resident) ----
  short8 B1[16];
#pragma unroll
  for (int ct = 0; ct < 4; ct++)
#pragma unroll
    for (int kc = 0; kc < 4; kc++)
      B1[ct * 4 + kc] =
          *(const short8*)&W1T[(size_t)(wv * 64 + ct * 16 + rA) * 128 + kc * 32 + kA];
  float b1v[4], lngv[4], lnbv[4];
#pragma unroll
  for (int ct = 0; ct < 4; ct++) {
    int col = wv * 64 + ct * 16 + rA;
    b1v[ct] = b1[col];
    lngv[ct] = lng[col];
    lnbv[ct] = lnb[col];
  }

  __syncthreads();

  // ---- GEMM1: C1[rt][ct] over 64 rows x 64 cols (per wave) ----
  f32x4 C1[16];
#pragma unroll
  for (int i = 0; i < 16; i++) C1[i] = (f32x4)0.0f;
#pragma unroll
  for (int rt = 0; rt < 4; rt++) {
#pragma unroll
    for (int kc = 0; kc < 4; kc++) {
      short8 A = *(const short8*)&yb[(rt * 16 + rA) * 136 + kc * 32 + kA];
#pragma unroll
      for (int ct = 0; ct < 4; ct++)
        C1[rt * 4 + ct] = __builtin_amdgcn_mfma_f32_16x16x32_bf16(A, B1[ct * 4 + kc],
                                                                  C1[rt * 4 + ct], 0, 0, 0);
    }
  }

  // ---- + b1; per-row partial sums (this wave's 64 cols) -> LDS atomics ----
#pragma unroll
  for (int rt = 0; rt < 4; rt++)
#pragma unroll
    for (int ct = 0; ct < 4; ct++)
#pragma unroll
      for (int j = 0; j < 4; j++) C1[rt * 4 + ct][j] += b1v[ct];

#pragma unroll
  for (int rt = 0; rt < 4; rt++) {
#pragma unroll
    for (int j = 0; j < 4; j++) {
      float p = C1[rt * 4 + 0][j] + C1[rt * 4 + 1][j] + C1[rt * 4 + 2][j] + C1[rt * 4 + 3][j];
      float q = C1[rt * 4 + 0][j] * C1[rt * 4 + 0][j];
      q = fmaf(C1[rt * 4 + 1][j], C1[rt * 4 + 1][j], q);
      q = fmaf(C1[rt * 4 + 2][j], C1[rt * 4 + 2][j], q);
      q = fmaf(C1[rt * 4 + 3][j], C1[rt * 4 + 3][j], q);
#pragma unroll
      for (int o = 1; o < 16; o <<= 1) {
        p += __shfl_xor(p, o);
        q += __shfl_xor(q, o);
      }
      if (rA == 0) {
        int row = rt * 16 + jrow + j;
        atomicAdd(&stats[row * 2 + 0], p);
        atomicAdd(&stats[row * 2 + 1], q);
      }
    }
  }
  __syncthreads();

  // ---- normalize + relu -> Hs (bf16) ----
#pragma unroll
  for (int rt = 0; rt < 4; rt++) {
#pragma unroll
    for (int j = 0; j < 4; j++) {
      int row = rt * 16 + jrow + j;
      float mean = stats[row * 2 + 0] * (1.0f / 256.0f);
      float var = stats[row * 2 + 1] * (1.0f / 256.0f) - mean * mean;
      float rstd = rsqrtf(var + 1e-5f);
#pragma unroll
      for (int ct = 0; ct < 4; ct++) {
        float v = fmaxf(fmaf((C1[rt * 4 + ct][j] - mean) * rstd, lngv[ct], lnbv[ct]), 0.0f);
        __hip_bfloat16 bv = __float2bfloat16(v);
        Hs[row * 264 + wv * 64 + ct * 16 + rA] = *(short*)&bv;
      }
    }
  }
  __syncthreads();

  // ---- B2 frags (cols wv*32 .. wv*32+31), register-resident ----
  short8 B2[16];
#pragma unroll
  for (int ct = 0; ct < 2; ct++)
#pragma unroll
    for (int kc = 0; kc < 8; kc++)
      B2[ct * 8 + kc] =
          *(const short8*)&W2T[(size_t)(wv * 32 + ct * 16 + rA) * 256 + kc * 32 + kA];
  float b2v[2];
#pragma unroll
  for (int ct = 0; ct < 2; ct++) b2v[ct] = b2[wv * 32 + ct * 16 + rA];

  // ---- GEMM2: C2[rt][ct2] over 64 rows x 32 cols (per wave) ----
  f32x4 C2[8];
#pragma unroll
  for (int i = 0; i < 8; i++) C2[i] = (f32x4)0.0f;
#pragma unroll
  for (int rt = 0; rt < 4; rt++) {
#pragma unroll
    for (int kc = 0; kc < 8; kc++) {
      short8 A = *(const short8*)&Hs[(rt * 16 + rA) * 264 + kc * 32 + kA];
#pragma unroll
      for (int ct = 0; ct < 2; ct++)
        C2[rt * 2 + ct] = __builtin_amdgcn_mfma_f32_16x16x32_bf16(A, B2[ct * 8 + kc],
                                                                  C2[rt * 2 + ct], 0, 0, 0);
    }
  }
  __syncthreads();  // all Hs/yb reads done; outst may alias them now

  // ---- stage C2 + b2 -> outst (f32, stride 133) ----
#pragma unroll
  for (int rt = 0; rt < 4; rt++)
#pragma unroll
    for (int ct = 0; ct < 2; ct++)
#pragma unroll
      for (int j = 0; j < 4; j++) {
        int row = rt * 16 + jrow + j;
        outst[row * 133 + wv * 32 + ct * 16 + rA] = C2[rt * 2 + ct][j] + b2v[ct];
      }
  __syncthreads();

  // ---- epilogue: y = outst + x, coalesced float4 ----
  {
    int r = tid >> 2;
    int c0 = (tid & 3) * 32;
    int gr = row0 + r;
    if (gr < M) {
#pragma unroll
      for (int i = 0; i < 8; i++) {
        float4 v = *(float4*)&outst[r * 133 + c0 + i * 4];
        const float4 xv = *(const float4*)(x + (size_t)gr * 128 + c0 + i * 4);
        float4 o;
        o.x = v.x + xv.x;
        o.y = v.y + xv.y;
        o.z = v.z + xv.z;
        o.w = v.w + xv.w;
        *(float4*)(y + (size_t)gr * 128 + c0 + i * 4) = o;
      }
    }
  }
}

// ---------------------------------------------------------------------------
extern "C" void kernel_launch(void* const* d_in, const int* in_sizes, int n_in,
                              void* d_out, int out_size, void* d_ws, size_t ws_size,
                              hipStream_t stream) {
  const int C = 128;
  const float* v_x = (const float*)d_in[0];
  const float* e_x = (const float*)d_in[1];
  const int* v_ei = (const int*)d_in[2];
  const int* e_ei = (const int*)d_in[3];
  const int N = in_sizes[0] / C;
  const int E = in_sizes[1] / C;
  const int LE = in_sizes[3] / 2;

  const float* ep[9];
  const float* np_[9];
  for (int i = 0; i < 9; i++) ep[i] = (const float*)d_in[4 + i];
  for (int i = 0; i < 9; i++) np_[i] = (const float*)d_in[13 + i];

  float* v_out = (float*)d_out;
  float* e_out = (float*)d_out + (size_t)N * C;

  char* wsp = (char*)d_ws;
  size_t o = 0;
  auto carve = [&](size_t bytes) {
    void* p = wsp + o;
    o += (bytes + 255) & ~(size_t)255;
    return p;
  };
  __hip_bfloat16* h = (__hip_bfloat16*)carve((size_t)E * C * 2);
  int* counts = (int*)carve((size_t)E * 4);
  int* off = (int*)carve(((size_t)E + 1) * 4);
  int* cursor = (int*)carve((size_t)E * 4);
  int* bsums = (int*)carve(4096);
  int* csr_src = (int*)carve((size_t)LE * 4);
  int* csr_eid = (int*)carve((size_t)LE * 4);
  short* eW1T = (short*)carve((size_t)256 * 128 * 2);
  short* eW2T = (short*)carve((size_t)128 * 256 * 2);
  short* nW1T = (short*)carve((size_t)256 * 128 * 2);
  short* nW2T = (short*)carve((size_t)128 * 256 * 2);
  (void)ws_size;
  (void)n_in;
  (void)out_size;

  auto run_layer = [&](const float* x, const int* ei, int M, int nnz, const float* eattr,
                       const float** P, short* W1T, short* W2T, float* outp) {
    const int* src = ei;
    const int* dst = ei + nnz;
    hipMemsetAsync(counts, 0, (size_t)M * 4, stream);
    wprep_kernel<<<256, 128, 0, stream>>>(P[3], W1T, 128, 256);
    wprep_kernel<<<128, 256, 0, stream>>>(P[7], W2T, 256, 128);
    ln_relu_kernel<<<(M + 3) / 4, 256, 0, stream>>>(x, P[0], P[1], h, M);
    count_kernel<<<(nnz + 255) / 256, 256, 0, stream>>>(dst, counts, nnz);
    int nb = (M + 1023) / 1024;
    scan_block_sums<<<nb, 256, 0, stream>>>(counts, bsums, M);
    scan_bsums<<<1, 512, 0, stream>>>(bsums, nb);
    scan_write<<<nb, 256, 0, stream>>>(counts, bsums, off, cursor, M, nnz);
    fill_kernel<<<(nnz + 255) / 256, 256, 0, stream>>>(src, dst, cursor, csr_src, csr_eid, nnz);
    if (eattr) {
      aggregate_kernel<true><<<(M + 3) / 4, 256, 0, stream>>>(h, off, csr_src, csr_eid,
                                                              eattr, P[2], outp, M);
    } else {
      aggregate_kernel<false><<<(M + 3) / 4, 256, 0, stream>>>(h, off, csr_src, csr_eid,
                                                               nullptr, P[2], outp, M);
    }
    mlp_kernel<<<(M + 63) / 64, 256, 0, stream>>>(x, outp, W1T, P[4], P[5], P[6], W2T,
                                                  P[8], M);
  };

  run_layer(e_x, e_ei, E, LE, nullptr, ep, eW1T, eW2T, e_out);
  run_layer(v_x, v_ei, N, E, e_out, np_, nW1T, nW2T, v_out);
}

// Round 5
// 567.891 us; speedup vs baseline: 3.1155x; 1.0187x over previous
//
#include <hip/hip_runtime.h>
#include <hip/hip_bf16.h>

#define GEN_EPS 1e-7f

typedef __attribute__((ext_vector_type(8))) short short8;
typedef __attribute__((ext_vector_type(4))) float f32x4;

// ---------------------------------------------------------------------------
// h = relu(LayerNorm(x)) stored as bf16.  One wave per row (C=128, 2 ch/lane).
// ---------------------------------------------------------------------------
__global__ void ln_relu_kernel(const float* __restrict__ x, const float* __restrict__ g,
                               const float* __restrict__ b, __hip_bfloat16* __restrict__ h,
                               int M) {
  int lane = threadIdx.x & 63;
  int r = blockIdx.x * 4 + (threadIdx.x >> 6);
  if (r >= M) return;
  float2 v = ((const float2*)(x + (size_t)r * 128))[lane];
  float s = v.x + v.y;
#pragma unroll
  for (int o = 32; o; o >>= 1) s += __shfl_xor(s, o);
  float m = s * (1.0f / 128.0f);
  float dx = v.x - m, dy = v.y - m;
  float q = dx * dx + dy * dy;
#pragma unroll
  for (int o = 32; o; o >>= 1) q += __shfl_xor(q, o);
  float rstd = rsqrtf(q * (1.0f / 128.0f) + 1e-5f);
  float2 gv = ((const float2*)g)[lane], bv = ((const float2*)b)[lane];
  float2 hv;
  hv.x = fmaxf(fmaf(dx * rstd, gv.x, bv.x), 0.0f);
  hv.y = fmaxf(fmaf(dy * rstd, gv.y, bv.y), 0.0f);
  ((__hip_bfloat162*)(h + (size_t)r * 128))[lane] = __float22bfloat162_rn(hv);
}

// ---------------------------------------------------------------------------
// Weight pack into MFMA-fragment order:
//   WP[(c>>4)*(16*R) + (k>>5)*512 + (c&15)*32 + (k&31)] = bf16(W[k][c])
// -> a wave's B-frag load for one (coltile, kchunk) is 1KB fully contiguous.
// ---------------------------------------------------------------------------
__global__ void wprep_kernel(const float* __restrict__ W, short* __restrict__ WP,
                             int R, int Cc) {
  int c = blockIdx.x;
  size_t tbase = (size_t)(c >> 4) * (size_t)(16 * R);
  int rsub = c & 15;
  for (int k = threadIdx.x; k < R; k += blockDim.x) {
    __hip_bfloat16 bv = __float2bfloat16(W[(size_t)k * Cc + c]);
    WP[tbase + (size_t)(k >> 5) * 512 + rsub * 32 + (k & 31)] = *(short*)&bv;
  }
}

// ---------------------------------------------------------------------------
// CSR construction: count -> scan -> fill
// ---------------------------------------------------------------------------
__global__ void count_kernel(const int* __restrict__ dst, int* __restrict__ counts, int nnz) {
  int i = blockIdx.x * blockDim.x + threadIdx.x;
  if (i < nnz) atomicAdd(&counts[dst[i]], 1);
}

__global__ void scan_block_sums(const int* __restrict__ counts, int* __restrict__ bsums, int M) {
  __shared__ int sm[256];
  int t = threadIdx.x;
  int base = blockIdx.x * 1024 + t * 4;
  int s = 0;
#pragma unroll
  for (int i = 0; i < 4; i++) {
    int idx = base + i;
    if (idx < M) s += counts[idx];
  }
  sm[t] = s;
  __syncthreads();
  for (int o = 128; o; o >>= 1) {
    if (t < o) sm[t] += sm[t + o];
    __syncthreads();
  }
  if (t == 0) bsums[blockIdx.x] = sm[0];
}

// one-block exclusive scan over up to 512 block sums
__global__ void scan_bsums(int* bsums, int nb) {
  __shared__ int sm[512];
  int t = threadIdx.x;
  int v = (t < nb) ? bsums[t] : 0;
  sm[t] = v;
  __syncthreads();
  for (int o = 1; o < 512; o <<= 1) {
    int u = (t >= o) ? sm[t - o] : 0;
    __syncthreads();
    sm[t] += u;
    __syncthreads();
  }
  if (t < nb) bsums[t] = sm[t] - v;  // exclusive
}

__global__ void scan_write(const int* __restrict__ counts, const int* __restrict__ bsums,
                           int* __restrict__ off, int* __restrict__ cursor, int M, int nnz) {
  __shared__ int sm[256];
  int t = threadIdx.x;
  int base = blockIdx.x * 1024 + t * 4;
  int c[4];
  int s = 0;
#pragma unroll
  for (int i = 0; i < 4; i++) {
    int idx = base + i;
    c[i] = (idx < M) ? counts[idx] : 0;
    s += c[i];
  }
  sm[t] = s;
  __syncthreads();
  for (int o = 1; o < 256; o <<= 1) {
    int v = (t >= o) ? sm[t - o] : 0;
    __syncthreads();
    sm[t] += v;
    __syncthreads();
  }
  int p = bsums[blockIdx.x] + sm[t] - s;
#pragma unroll
  for (int i = 0; i < 4; i++) {
    int idx = base + i;
    if (idx < M) {
      off[idx] = p;
      cursor[idx] = p;
      p += c[i];
    }
  }
  if (blockIdx.x == 0 && t == 0) off[M] = nnz;
}

__global__ void fill_kernel(const int* __restrict__ src, const int* __restrict__ dst,
                            int* __restrict__ cursor, int* __restrict__ csr_src,
                            int* __restrict__ csr_eid, int nnz) {
  int i = blockIdx.x * blockDim.x + threadIdx.x;
  if (i >= nnz) return;
  int d = dst[i];
  int p = atomicAdd(&cursor[d], 1);
  csr_src[p] = src[i];
  csr_eid[p] = i;
}

// ---------------------------------------------------------------------------
// Softmax aggregation, one wave per destination row, 2 channels per lane.
// Writes y bf16 PRE-PACKED in MFMA fragment order:
//   uint index = (r>>4)*1024 + (lane>>4)*256 + (r&15)*16 + (lane&15)
// so the MLP's A-frag loads are fully coalesced.
// ---------------------------------------------------------------------------
template <bool HAS_EATTR>
__global__ __launch_bounds__(256) void aggregate_kernel(
    const __hip_bfloat16* __restrict__ h, const int* __restrict__ off,
    const int* __restrict__ csr_src, const int* __restrict__ csr_eid,
    const float* __restrict__ eattr, const float* __restrict__ tptr,
    uint* __restrict__ yP, int M) {
  int lane = threadIdx.x & 63;
  int r = blockIdx.x * 4 + (threadIdx.x >> 6);
  if (r >= M) return;
  const float t = tptr[0];
  float2 hv = __bfloat1622float2(((const __hip_bfloat162*)(h + (size_t)r * 128))[lane]);
  int e0 = off[r], e1 = off[r + 1];
  float d0 = 0.0f, d1 = 0.0f, a0 = 0.0f, a1 = 0.0f;
  int sN = 0, idN = 0;
  if (e0 < e1) {
    sN = csr_src[e0];
    if (HAS_EATTR) idN = csr_eid[e0];
  }
  for (int e = e0; e < e1; e++) {
    int s = sN, id = idN;
    if (e + 1 < e1) {
      sN = csr_src[e + 1];
      if (HAS_EATTR) idN = csr_eid[e + 1];
    }
    float2 mv = __bfloat1622float2(((const __hip_bfloat162*)(h + (size_t)s * 128))[lane]);
    if (HAS_EATTR) {
      float2 ea = ((const float2*)(eattr + (size_t)id * 128))[lane];
      mv.x += ea.x;
      mv.y += ea.y;
    }
    float m0 = fmaxf(mv.x, 0.0f) + GEN_EPS;
    float m1 = fmaxf(mv.y, 0.0f) + GEN_EPS;
    float al0 = __expf(m0 * t), al1 = __expf(m1 * t);
    d0 += al0;
    d1 += al1;
    a0 = fmaf(al0, m0, a0);
    a1 = fmaf(al1, m1, a1);
  }
  float2 yv;
  yv.x = (e1 > e0 ? a0 / d0 : 0.0f) + hv.x;
  yv.y = (e1 > e0 ? a1 / d1 : 0.0f) + hv.y;
  __hip_bfloat162 yb2 = __float22bfloat162_rn(yv);
  yP[(r >> 4) * 1024 + (lane >> 4) * 256 + (r & 15) * 16 + (lane & 15)] = *(uint*)&yb2;
}

// ---------------------------------------------------------------------------
// MLP: 64 rows / 4 waves per block.  A-frags straight from packed global yP;
// B-frags streamed from packed W (coalesced 1KB/wave loads); only the hidden
// H goes through LDS (needed cross-wave for GEMM2's K=256).
//   GEMM1 (N-split: wave owns 64 hid cols) -> +b1 -> LN (shfl + LDS atomics)
//   -> relu -> Hs (bf16) -> GEMM2 (wave owns 32 out cols) -> direct epilogue.
// ---------------------------------------------------------------------------
__global__ __launch_bounds__(256, 3) void mlp_kernel(
    const float* __restrict__ x, const short* __restrict__ yP,
    const short* __restrict__ W1P, const float* __restrict__ b1,
    const float* __restrict__ lng, const float* __restrict__ lnb,
    const short* __restrict__ W2P, const float* __restrict__ b2,
    float* __restrict__ out, int M) {
  __shared__ short Hs[64 * 264];
  __shared__ float stats[128];
  const int tid = threadIdx.x, lane = tid & 63, wv = tid >> 6;
  const int row0 = blockIdx.x * 64;
  const int rA = lane & 15, hi = lane >> 4;
  const int kA = hi * 8, jrow = hi * 4;

  if (tid < 128) stats[tid] = 0.0f;

  // per-col params for this wave's GEMM1 columns
  float b1v[4], lngv[4], lnbv[4];
#pragma unroll
  for (int ct = 0; ct < 4; ct++) {
    int col = wv * 64 + ct * 16 + rA;
    b1v[ct] = b1[col];
    lngv[ct] = lng[col];
    lnbv[ct] = lnb[col];
  }

  // ---- GEMM1: C1[rt*4+ct], A from packed yP, B from packed W1P ----
  const short* ybase = yP + (size_t)(row0 >> 4) * 2048;
  const short* w1base = W1P + (size_t)(wv * 4) * 2048;
  const int fo = rA * 32 + kA;  // within-chunk fragment offset
  f32x4 C1[16];
#pragma unroll
  for (int i = 0; i < 16; i++) C1[i] = (f32x4)0.0f;
#pragma unroll 2
  for (int kc = 0; kc < 4; kc++) {
    short8 a0 = *(const short8*)&ybase[0 * 2048 + kc * 512 + fo];
    short8 a1 = *(const short8*)&ybase[1 * 2048 + kc * 512 + fo];
    short8 a2 = *(const short8*)&ybase[2 * 2048 + kc * 512 + fo];
    short8 a3 = *(const short8*)&ybase[3 * 2048 + kc * 512 + fo];
    short8 w0 = *(const short8*)&w1base[0 * 2048 + kc * 512 + fo];
    short8 w1 = *(const short8*)&w1base[1 * 2048 + kc * 512 + fo];
    short8 w2 = *(const short8*)&w1base[2 * 2048 + kc * 512 + fo];
    short8 w3 = *(const short8*)&w1base[3 * 2048 + kc * 512 + fo];
    C1[0] = __builtin_amdgcn_mfma_f32_16x16x32_bf16(a0, w0, C1[0], 0, 0, 0);
    C1[1] = __builtin_amdgcn_mfma_f32_16x16x32_bf16(a0, w1, C1[1], 0, 0, 0);
    C1[2] = __builtin_amdgcn_mfma_f32_16x16x32_bf16(a0, w2, C1[2], 0, 0, 0);
    C1[3] = __builtin_amdgcn_mfma_f32_16x16x32_bf16(a0, w3, C1[3], 0, 0, 0);
    C1[4] = __builtin_amdgcn_mfma_f32_16x16x32_bf16(a1, w0, C1[4], 0, 0, 0);
    C1[5] = __builtin_amdgcn_mfma_f32_16x16x32_bf16(a1, w1, C1[5], 0, 0, 0);
    C1[6] = __builtin_amdgcn_mfma_f32_16x16x32_bf16(a1, w2, C1[6], 0, 0, 0);
    C1[7] = __builtin_amdgcn_mfma_f32_16x16x32_bf16(a1, w3, C1[7], 0, 0, 0);
    C1[8] = __builtin_amdgcn_mfma_f32_16x16x32_bf16(a2, w0, C1[8], 0, 0, 0);
    C1[9] = __builtin_amdgcn_mfma_f32_16x16x32_bf16(a2, w1, C1[9], 0, 0, 0);
    C1[10] = __builtin_amdgcn_mfma_f32_16x16x32_bf16(a2, w2, C1[10], 0, 0, 0);
    C1[11] = __builtin_amdgcn_mfma_f32_16x16x32_bf16(a2, w3, C1[11], 0, 0, 0);
    C1[12] = __builtin_amdgcn_mfma_f32_16x16x32_bf16(a3, w0, C1[12], 0, 0, 0);
    C1[13] = __builtin_amdgcn_mfma_f32_16x16x32_bf16(a3, w1, C1[13], 0, 0, 0);
    C1[14] = __builtin_amdgcn_mfma_f32_16x16x32_bf16(a3, w2, C1[14], 0, 0, 0);
    C1[15] = __builtin_amdgcn_mfma_f32_16x16x32_bf16(a3, w3, C1[15], 0, 0, 0);
  }

  // ---- + b1; per-row partial sums -> LDS atomics ----
#pragma unroll
  for (int rt = 0; rt < 4; rt++)
#pragma unroll
    for (int ct = 0; ct < 4; ct++)
#pragma unroll
      for (int j = 0; j < 4; j++) C1[rt * 4 + ct][j] += b1v[ct];

  __syncthreads();  // stats init visible before atomics

#pragma unroll
  for (int rt = 0; rt < 4; rt++) {
#pragma unroll
    for (int j = 0; j < 4; j++) {
      float p = C1[rt * 4 + 0][j] + C1[rt * 4 + 1][j] + C1[rt * 4 + 2][j] + C1[rt * 4 + 3][j];
      float q = C1[rt * 4 + 0][j] * C1[rt * 4 + 0][j];
      q = fmaf(C1[rt * 4 + 1][j], C1[rt * 4 + 1][j], q);
      q = fmaf(C1[rt * 4 + 2][j], C1[rt * 4 + 2][j], q);
      q = fmaf(C1[rt * 4 + 3][j], C1[rt * 4 + 3][j], q);
#pragma unroll
      for (int o = 1; o < 16; o <<= 1) {
        p += __shfl_xor(p, o);
        q += __shfl_xor(q, o);
      }
      if (rA == 0) {
        int row = rt * 16 + jrow + j;
        atomicAdd(&stats[row * 2 + 0], p);
        atomicAdd(&stats[row * 2 + 1], q);
      }
    }
  }
  __syncthreads();

  // ---- normalize + relu -> Hs (bf16, stride 264) ----
#pragma unroll
  for (int rt = 0; rt < 4; rt++) {
#pragma unroll
    for (int j = 0; j < 4; j++) {
      int row = rt * 16 + jrow + j;
      float mean = stats[row * 2 + 0] * (1.0f / 256.0f);
      float var = stats[row * 2 + 1] * (1.0f / 256.0f) - mean * mean;
      float rstd = rsqrtf(var + 1e-5f);
#pragma unroll
      for (int ct = 0; ct < 4; ct++) {
        float v = fmaxf(fmaf((C1[rt * 4 + ct][j] - mean) * rstd, lngv[ct], lnbv[ct]), 0.0f);
        __hip_bfloat16 bv = __float2bfloat16(v);
        Hs[row * 264 + wv * 64 + ct * 16 + rA] = *(short*)&bv;
      }
    }
  }
  __syncthreads();

  // ---- GEMM2: A from Hs (LDS), B from packed W2P ----
  const short* w2base = W2P + (size_t)(wv * 2) * 4096;
  f32x4 C2[8];
#pragma unroll
  for (int i = 0; i < 8; i++) C2[i] = (f32x4)0.0f;
#pragma unroll 2
  for (int kc = 0; kc < 8; kc++) {
    short8 a0 = *(const short8*)&Hs[(0 * 16 + rA) * 264 + kc * 32 + kA];
    short8 a1 = *(const short8*)&Hs[(1 * 16 + rA) * 264 + kc * 32 + kA];
    short8 a2 = *(const short8*)&Hs[(2 * 16 + rA) * 264 + kc * 32 + kA];
    short8 a3 = *(const short8*)&Hs[(3 * 16 + rA) * 264 + kc * 32 + kA];
    short8 w0 = *(const short8*)&w2base[0 * 4096 + kc * 512 + fo];
    short8 w1 = *(const short8*)&w2base[1 * 4096 + kc * 512 + fo];
    C2[0] = __builtin_amdgcn_mfma_f32_16x16x32_bf16(a0, w0, C2[0], 0, 0, 0);
    C2[1] = __builtin_amdgcn_mfma_f32_16x16x32_bf16(a0, w1, C2[1], 0, 0, 0);
    C2[2] = __builtin_amdgcn_mfma_f32_16x16x32_bf16(a1, w0, C2[2], 0, 0, 0);
    C2[3] = __builtin_amdgcn_mfma_f32_16x16x32_bf16(a1, w1, C2[3], 0, 0, 0);
    C2[4] = __builtin_amdgcn_mfma_f32_16x16x32_bf16(a2, w0, C2[4], 0, 0, 0);
    C2[5] = __builtin_amdgcn_mfma_f32_16x16x32_bf16(a2, w1, C2[5], 0, 0, 0);
    C2[6] = __builtin_amdgcn_mfma_f32_16x16x32_bf16(a3, w0, C2[6], 0, 0, 0);
    C2[7] = __builtin_amdgcn_mfma_f32_16x16x32_bf16(a3, w1, C2[7], 0, 0, 0);
  }

  // ---- direct epilogue: out = C2 + b2 + x ----
  float b2v[2];
#pragma unroll
  for (int ct = 0; ct < 2; ct++) b2v[ct] = b2[wv * 32 + ct * 16 + rA];
#pragma unroll
  for (int rt = 0; rt < 4; rt++) {
#pragma unroll
    for (int j = 0; j < 4; j++) {
      int row = row0 + rt * 16 + jrow + j;
      if (row < M) {
#pragma unroll
        for (int ct = 0; ct < 2; ct++) {
          size_t idx = (size_t)row * 128 + wv * 32 + ct * 16 + rA;
          out[idx] = C2[rt * 2 + ct][j] + b2v[ct] + x[idx];
        }
      }
    }
  }
}

// ---------------------------------------------------------------------------
extern "C" void kernel_launch(void* const* d_in, const int* in_sizes, int n_in,
                              void* d_out, int out_size, void* d_ws, size_t ws_size,
                              hipStream_t stream) {
  const int C = 128;
  const float* v_x = (const float*)d_in[0];
  const float* e_x = (const float*)d_in[1];
  const int* v_ei = (const int*)d_in[2];
  const int* e_ei = (const int*)d_in[3];
  const int N = in_sizes[0] / C;
  const int E = in_sizes[1] / C;
  const int LE = in_sizes[3] / 2;

  const float* ep[9];
  const float* np_[9];
  for (int i = 0; i < 9; i++) ep[i] = (const float*)d_in[4 + i];
  for (int i = 0; i < 9; i++) np_[i] = (const float*)d_in[13 + i];

  float* v_out = (float*)d_out;
  float* e_out = (float*)d_out + (size_t)N * C;

  char* wsp = (char*)d_ws;
  size_t o = 0;
  auto carve = [&](size_t bytes) {
    void* p = wsp + o;
    o += (bytes + 255) & ~(size_t)255;
    return p;
  };
  short* yPbuf = (short*)carve((size_t)E * C * 2);  // packed bf16 y
  int* counts = (int*)carve((size_t)E * 4);
  int* off = (int*)carve(((size_t)E + 1) * 4);
  int* cursor = (int*)carve((size_t)E * 4);
  int* bsums = (int*)carve(4096);
  int* csr_src = (int*)carve((size_t)LE * 4);
  int* csr_eid = (int*)carve((size_t)LE * 4);
  short* eW1P = (short*)carve((size_t)256 * 128 * 2);
  short* eW2P = (short*)carve((size_t)128 * 256 * 2);
  short* nW1P = (short*)carve((size_t)256 * 128 * 2);
  short* nW2P = (short*)carve((size_t)128 * 256 * 2);
  (void)ws_size;
  (void)n_in;
  (void)out_size;

  // h lives in the (fp32-sized) output region as bf16; dead before mlp writes.
  auto run_layer = [&](const float* x, const int* ei, int M, int nnz, const float* eattr,
                       const float** P, short* W1P, short* W2P, float* outp) {
    const int* src = ei;
    const int* dst = ei + nnz;
    __hip_bfloat16* h = (__hip_bfloat16*)outp;
    hipMemsetAsync(counts, 0, (size_t)M * 4, stream);
    wprep_kernel<<<256, 128, 0, stream>>>(P[3], W1P, 128, 256);
    wprep_kernel<<<128, 256, 0, stream>>>(P[7], W2P, 256, 128);
    ln_relu_kernel<<<(M + 3) / 4, 256, 0, stream>>>(x, P[0], P[1], h, M);
    count_kernel<<<(nnz + 255) / 256, 256, 0, stream>>>(dst, counts, nnz);
    int nb = (M + 1023) / 1024;
    scan_block_sums<<<nb, 256, 0, stream>>>(counts, bsums, M);
    scan_bsums<<<1, 512, 0, stream>>>(bsums, nb);
    scan_write<<<nb, 256, 0, stream>>>(counts, bsums, off, cursor, M, nnz);
    fill_kernel<<<(nnz + 255) / 256, 256, 0, stream>>>(src, dst, cursor, csr_src, csr_eid, nnz);
    if (eattr) {
      aggregate_kernel<true><<<(M + 3) / 4, 256, 0, stream>>>(h, off, csr_src, csr_eid,
                                                              eattr, P[2], (uint*)yPbuf, M);
    } else {
      aggregate_kernel<false><<<(M + 3) / 4, 256, 0, stream>>>(h, off, csr_src, csr_eid,
                                                               nullptr, P[2], (uint*)yPbuf, M);
    }
    mlp_kernel<<<(M + 63) / 64, 256, 0, stream>>>(x, yPbuf, W1P, P[4], P[5], P[6], W2P,
                                                  P[8], outp, M);
  };

  run_layer(e_x, e_ei, E, LE, nullptr, ep, eW1P, eW2P, e_out);
  run_layer(v_x, v_ei, N, E, e_out, np_, nW1P, nW2P, v_out);
}

// Round 6
// 515.259 us; speedup vs baseline: 3.4337x; 1.1021x over previous
//
#include <hip/hip_runtime.h>
#include <hip/hip_bf16.h>

#define GEN_EPS 1e-7f

typedef __attribute__((ext_vector_type(8))) short short8;
typedef __attribute__((ext_vector_type(4))) float f32x4;

// ---------------------------------------------------------------------------
// h = relu(LayerNorm(x)) stored as bf16.  One wave per row (C=128, 2 ch/lane).
// ---------------------------------------------------------------------------
__global__ void ln_relu_kernel(const float* __restrict__ x, const float* __restrict__ g,
                               const float* __restrict__ b, __hip_bfloat16* __restrict__ h,
                               int M) {
  int lane = threadIdx.x & 63;
  int r = blockIdx.x * 4 + (threadIdx.x >> 6);
  if (r >= M) return;
  float2 v = ((const float2*)(x + (size_t)r * 128))[lane];
  float s = v.x + v.y;
#pragma unroll
  for (int o = 32; o; o >>= 1) s += __shfl_xor(s, o);
  float m = s * (1.0f / 128.0f);
  float dx = v.x - m, dy = v.y - m;
  float q = dx * dx + dy * dy;
#pragma unroll
  for (int o = 32; o; o >>= 1) q += __shfl_xor(q, o);
  float rstd = rsqrtf(q * (1.0f / 128.0f) + 1e-5f);
  float2 gv = ((const float2*)g)[lane], bv = ((const float2*)b)[lane];
  float2 hv;
  hv.x = fmaxf(fmaf(dx * rstd, gv.x, bv.x), 0.0f);
  hv.y = fmaxf(fmaf(dy * rstd, gv.y, bv.y), 0.0f);
  ((__hip_bfloat162*)(h + (size_t)r * 128))[lane] = __float22bfloat162_rn(hv);
}

// ---------------------------------------------------------------------------
// Weight pack into MFMA-fragment order:
//   WP[(c>>4)*(16*R) + (k>>5)*512 + (c&15)*32 + (k&31)] = bf16(W[k][c])
// ---------------------------------------------------------------------------
__global__ void wprep_kernel(const float* __restrict__ W, short* __restrict__ WP,
                             int R, int Cc) {
  int c = blockIdx.x;
  size_t tbase = (size_t)(c >> 4) * (size_t)(16 * R);
  int rsub = c & 15;
  for (int k = threadIdx.x; k < R; k += blockDim.x) {
    __hip_bfloat16 bv = __float2bfloat16(W[(size_t)k * Cc + c]);
    WP[tbase + (size_t)(k >> 5) * 512 + rsub * 32 + (k & 31)] = *(short*)&bv;
  }
}

// ---------------------------------------------------------------------------
// CSR construction: count -> scan -> fill
// ---------------------------------------------------------------------------
__global__ void count_kernel(const int* __restrict__ dst, int* __restrict__ counts, int nnz) {
  int i = blockIdx.x * blockDim.x + threadIdx.x;
  if (i < nnz) atomicAdd(&counts[dst[i]], 1);
}

__global__ void scan_block_sums(const int* __restrict__ counts, int* __restrict__ bsums, int M) {
  __shared__ int sm[256];
  int t = threadIdx.x;
  int base = blockIdx.x * 1024 + t * 4;
  int s = 0;
#pragma unroll
  for (int i = 0; i < 4; i++) {
    int idx = base + i;
    if (idx < M) s += counts[idx];
  }
  sm[t] = s;
  __syncthreads();
  for (int o = 128; o; o >>= 1) {
    if (t < o) sm[t] += sm[t + o];
    __syncthreads();
  }
  if (t == 0) bsums[blockIdx.x] = sm[0];
}

// one-block exclusive scan over up to 512 block sums
__global__ void scan_bsums(int* bsums, int nb) {
  __shared__ int sm[512];
  int t = threadIdx.x;
  int v = (t < nb) ? bsums[t] : 0;
  sm[t] = v;
  __syncthreads();
  for (int o = 1; o < 512; o <<= 1) {
    int u = (t >= o) ? sm[t - o] : 0;
    __syncthreads();
    sm[t] += u;
    __syncthreads();
  }
  if (t < nb) bsums[t] = sm[t] - v;  // exclusive
}

__global__ void scan_write(const int* __restrict__ counts, const int* __restrict__ bsums,
                           int* __restrict__ off, int* __restrict__ cursor, int M, int nnz) {
  __shared__ int sm[256];
  int t = threadIdx.x;
  int base = blockIdx.x * 1024 + t * 4;
  int c[4];
  int s = 0;
#pragma unroll
  for (int i = 0; i < 4; i++) {
    int idx = base + i;
    c[i] = (idx < M) ? counts[idx] : 0;
    s += c[i];
  }
  sm[t] = s;
  __syncthreads();
  for (int o = 1; o < 256; o <<= 1) {
    int v = (t >= o) ? sm[t - o] : 0;
    __syncthreads();
    sm[t] += v;
    __syncthreads();
  }
  int p = bsums[blockIdx.x] + sm[t] - s;
#pragma unroll
  for (int i = 0; i < 4; i++) {
    int idx = base + i;
    if (idx < M) {
      off[idx] = p;
      cursor[idx] = p;
      p += c[i];
    }
  }
  if (blockIdx.x == 0 && t == 0) off[M] = nnz;
}

template <bool HAS_EID>
__global__ void fill_kernel(const int* __restrict__ src, const int* __restrict__ dst,
                            int* __restrict__ cursor, int* __restrict__ csr_src,
                            int* __restrict__ csr_eid, int nnz) {
  int i = blockIdx.x * blockDim.x + threadIdx.x;
  if (i >= nnz) return;
  int d = dst[i];
  int p = atomicAdd(&cursor[d], 1);
  csr_src[p] = src[i];
  if (HAS_EID) csr_eid[p] = i;
}

// ---------------------------------------------------------------------------
// Softmax aggregation, one wave per destination row, 2 channels per lane.
// Writes y bf16 PRE-PACKED in MFMA fragment order.
// ---------------------------------------------------------------------------
template <bool HAS_EATTR>
__global__ __launch_bounds__(256) void aggregate_kernel(
    const __hip_bfloat16* __restrict__ h, const int* __restrict__ off,
    const int* __restrict__ csr_src, const int* __restrict__ csr_eid,
    const float* __restrict__ eattr, const float* __restrict__ tptr,
    uint* __restrict__ yP, int M) {
  int lane = threadIdx.x & 63;
  int r = blockIdx.x * 4 + (threadIdx.x >> 6);
  if (r >= M) return;
  const float t = tptr[0];
  float2 hv = __bfloat1622float2(((const __hip_bfloat162*)(h + (size_t)r * 128))[lane]);
  int e0 = off[r], e1 = off[r + 1];
  float d0 = 0.0f, d1 = 0.0f, a0 = 0.0f, a1 = 0.0f;
  int sN = 0, idN = 0;
  if (e0 < e1) {
    sN = csr_src[e0];
    if (HAS_EATTR) idN = csr_eid[e0];
  }
  for (int e = e0; e < e1; e++) {
    int s = sN, id = idN;
    if (e + 1 < e1) {
      sN = csr_src[e + 1];
      if (HAS_EATTR) idN = csr_eid[e + 1];
    }
    float2 mv = __bfloat1622float2(((const __hip_bfloat162*)(h + (size_t)s * 128))[lane]);
    if (HAS_EATTR) {
      float2 ea = ((const float2*)(eattr + (size_t)id * 128))[lane];
      mv.x += ea.x;
      mv.y += ea.y;
    }
    float m0 = fmaxf(mv.x, 0.0f) + GEN_EPS;
    float m1 = fmaxf(mv.y, 0.0f) + GEN_EPS;
    float al0 = __expf(m0 * t), al1 = __expf(m1 * t);
    d0 += al0;
    d1 += al1;
    a0 = fmaf(al0, m0, a0);
    a1 = fmaf(al1, m1, a1);
  }
  float2 yv;
  yv.x = (e1 > e0 ? a0 / d0 : 0.0f) + hv.x;
  yv.y = (e1 > e0 ? a1 / d1 : 0.0f) + hv.y;
  __hip_bfloat162 yb2 = __float22bfloat162_rn(yv);
  yP[(r >> 4) * 1024 + (lane >> 4) * 256 + (r & 15) * 16 + (lane & 15)] = *(uint*)&yb2;
}

// ---------------------------------------------------------------------------
// MLP: 32 rows / 4 waves per block (N-split: wave owns 64 hid cols, 32 out
// cols).  Small state -> high occupancy; x residual prefetched after GEMM1
// so its HBM latency hides under LN + barriers + GEMM2.
// ---------------------------------------------------------------------------
__global__ __launch_bounds__(256, 3) void mlp_kernel(
    const float* __restrict__ x, const short* __restrict__ yP,
    const short* __restrict__ W1P, const float* __restrict__ b1,
    const float* __restrict__ lng, const float* __restrict__ lnb,
    const short* __restrict__ W2P, const float* __restrict__ b2,
    float* __restrict__ out, int M) {
  __shared__ short Hs[32 * 268];
  __shared__ float stats[64];
  const int tid = threadIdx.x, lane = tid & 63, wv = tid >> 6;
  const int row0 = blockIdx.x * 32;
  const int rA = lane & 15, hi = lane >> 4;
  const int kA = hi * 8, jrow = hi * 4;

  if (tid < 64) stats[tid] = 0.0f;

  float b1v[4], lngv[4], lnbv[4];
#pragma unroll
  for (int ct = 0; ct < 4; ct++) {
    int col = wv * 64 + ct * 16 + rA;
    b1v[ct] = b1[col];
    lngv[ct] = lng[col];
    lnbv[ct] = lnb[col];
  }

  // ---- GEMM1: 32 rows x 64 cols per wave ----
  const short* ybase = yP + (size_t)(row0 >> 4) * 2048;
  const short* w1base = W1P + (size_t)(wv * 4) * 2048;
  const int fo = rA * 32 + kA;
  f32x4 C1[8];
#pragma unroll
  for (int i = 0; i < 8; i++) C1[i] = (f32x4)0.0f;
#pragma unroll
  for (int kc = 0; kc < 4; kc++) {
    short8 a0 = *(const short8*)&ybase[0 * 2048 + kc * 512 + fo];
    short8 a1 = *(const short8*)&ybase[1 * 2048 + kc * 512 + fo];
    short8 w0 = *(const short8*)&w1base[0 * 2048 + kc * 512 + fo];
    short8 w1 = *(const short8*)&w1base[1 * 2048 + kc * 512 + fo];
    short8 w2 = *(const short8*)&w1base[2 * 2048 + kc * 512 + fo];
    short8 w3 = *(const short8*)&w1base[3 * 2048 + kc * 512 + fo];
    C1[0] = __builtin_amdgcn_mfma_f32_16x16x32_bf16(a0, w0, C1[0], 0, 0, 0);
    C1[1] = __builtin_amdgcn_mfma_f32_16x16x32_bf16(a0, w1, C1[1], 0, 0, 0);
    C1[2] = __builtin_amdgcn_mfma_f32_16x16x32_bf16(a0, w2, C1[2], 0, 0, 0);
    C1[3] = __builtin_amdgcn_mfma_f32_16x16x32_bf16(a0, w3, C1[3], 0, 0, 0);
    C1[4] = __builtin_amdgcn_mfma_f32_16x16x32_bf16(a1, w0, C1[4], 0, 0, 0);
    C1[5] = __builtin_amdgcn_mfma_f32_16x16x32_bf16(a1, w1, C1[5], 0, 0, 0);
    C1[6] = __builtin_amdgcn_mfma_f32_16x16x32_bf16(a1, w2, C1[6], 0, 0, 0);
    C1[7] = __builtin_amdgcn_mfma_f32_16x16x32_bf16(a1, w3, C1[7], 0, 0, 0);
  }

  // ---- x residual prefetch (latency hidden under LN + GEMM2) ----
  float xv[16];
#pragma unroll
  for (int rt = 0; rt < 2; rt++)
#pragma unroll
    for (int ct = 0; ct < 2; ct++)
#pragma unroll
      for (int j = 0; j < 4; j++) {
        int row = row0 + rt * 16 + jrow + j;
        xv[rt * 8 + ct * 4 + j] =
            (row < M) ? x[(size_t)row * 128 + wv * 32 + ct * 16 + rA] : 0.0f;
      }

  // ---- + b1; per-row partial sums -> LDS atomics ----
#pragma unroll
  for (int rt = 0; rt < 2; rt++)
#pragma unroll
    for (int ct = 0; ct < 4; ct++)
#pragma unroll
      for (int j = 0; j < 4; j++) C1[rt * 4 + ct][j] += b1v[ct];

  __syncthreads();  // stats init visible before atomics

#pragma unroll
  for (int rt = 0; rt < 2; rt++) {
#pragma unroll
    for (int j = 0; j < 4; j++) {
      float p = C1[rt * 4 + 0][j] + C1[rt * 4 + 1][j] + C1[rt * 4 + 2][j] + C1[rt * 4 + 3][j];
      float q = C1[rt * 4 + 0][j] * C1[rt * 4 + 0][j];
      q = fmaf(C1[rt * 4 + 1][j], C1[rt * 4 + 1][j], q);
      q = fmaf(C1[rt * 4 + 2][j], C1[rt * 4 + 2][j], q);
      q = fmaf(C1[rt * 4 + 3][j], C1[rt * 4 + 3][j], q);
#pragma unroll
      for (int o = 1; o < 16; o <<= 1) {
        p += __shfl_xor(p, o);
        q += __shfl_xor(q, o);
      }
      if (rA == 0) {
        int row = rt * 16 + jrow + j;
        atomicAdd(&stats[row * 2 + 0], p);
        atomicAdd(&stats[row * 2 + 1], q);
      }
    }
  }
  __syncthreads();

  // ---- normalize + relu -> Hs (bf16, stride 268) ----
#pragma unroll
  for (int rt = 0; rt < 2; rt++) {
#pragma unroll
    for (int j = 0; j < 4; j++) {
      int row = rt * 16 + jrow + j;
      float mean = stats[row * 2 + 0] * (1.0f / 256.0f);
      float var = stats[row * 2 + 1] * (1.0f / 256.0f) - mean * mean;
      float rstd = rsqrtf(var + 1e-5f);
#pragma unroll
      for (int ct = 0; ct < 4; ct++) {
        float v = fmaxf(fmaf((C1[rt * 4 + ct][j] - mean) * rstd, lngv[ct], lnbv[ct]), 0.0f);
        __hip_bfloat16 bv = __float2bfloat16(v);
        Hs[row * 268 + wv * 64 + ct * 16 + rA] = *(short*)&bv;
      }
    }
  }
  __syncthreads();

  // ---- GEMM2: A from Hs (LDS), B from packed W2P ----
  const short* w2base = W2P + (size_t)(wv * 2) * 4096;
  f32x4 C2[4];
#pragma unroll
  for (int i = 0; i < 4; i++) C2[i] = (f32x4)0.0f;
#pragma unroll
  for (int kc = 0; kc < 8; kc++) {
    short8 a0 = *(const short8*)&Hs[rA * 268 + kc * 32 + kA];
    short8 a1 = *(const short8*)&Hs[(16 + rA) * 268 + kc * 32 + kA];
    short8 w0 = *(const short8*)&w2base[0 * 4096 + kc * 512 + fo];
    short8 w1 = *(const short8*)&w2base[1 * 4096 + kc * 512 + fo];
    C2[0] = __builtin_amdgcn_mfma_f32_16x16x32_bf16(a0, w0, C2[0], 0, 0, 0);
    C2[1] = __builtin_amdgcn_mfma_f32_16x16x32_bf16(a0, w1, C2[1], 0, 0, 0);
    C2[2] = __builtin_amdgcn_mfma_f32_16x16x32_bf16(a1, w0, C2[2], 0, 0, 0);
    C2[3] = __builtin_amdgcn_mfma_f32_16x16x32_bf16(a1, w1, C2[3], 0, 0, 0);
  }

  // ---- epilogue: out = C2 + b2 + xv ----
  float b2v[2];
#pragma unroll
  for (int ct = 0; ct < 2; ct++) b2v[ct] = b2[wv * 32 + ct * 16 + rA];
#pragma unroll
  for (int rt = 0; rt < 2; rt++) {
#pragma unroll
    for (int j = 0; j < 4; j++) {
      int row = row0 + rt * 16 + jrow + j;
      if (row < M) {
#pragma unroll
        for (int ct = 0; ct < 2; ct++) {
          size_t idx = (size_t)row * 128 + wv * 32 + ct * 16 + rA;
          out[idx] = C2[rt * 2 + ct][j] + b2v[ct] + xv[rt * 8 + ct * 4 + j];
        }
      }
    }
  }
}

// ---------------------------------------------------------------------------
extern "C" void kernel_launch(void* const* d_in, const int* in_sizes, int n_in,
                              void* d_out, int out_size, void* d_ws, size_t ws_size,
                              hipStream_t stream) {
  const int C = 128;
  const float* v_x = (const float*)d_in[0];
  const float* e_x = (const float*)d_in[1];
  const int* v_ei = (const int*)d_in[2];
  const int* e_ei = (const int*)d_in[3];
  const int N = in_sizes[0] / C;
  const int E = in_sizes[1] / C;
  const int LE = in_sizes[3] / 2;

  const float* ep[9];
  const float* np_[9];
  for (int i = 0; i < 9; i++) ep[i] = (const float*)d_in[4 + i];
  for (int i = 0; i < 9; i++) np_[i] = (const float*)d_in[13 + i];

  float* v_out = (float*)d_out;
  float* e_out = (float*)d_out + (size_t)N * C;

  char* wsp = (char*)d_ws;
  size_t o = 0;
  auto carve = [&](size_t bytes) {
    void* p = wsp + o;
    o += (bytes + 255) & ~(size_t)255;
    return p;
  };
  short* yPbuf = (short*)carve((size_t)E * C * 2);  // packed bf16 y
  int* counts = (int*)carve((size_t)E * 4);
  int* off = (int*)carve(((size_t)E + 1) * 4);
  int* cursor = (int*)carve((size_t)E * 4);
  int* bsums = (int*)carve(4096);
  int* csr_src = (int*)carve((size_t)LE * 4);
  int* csr_eid = (int*)carve((size_t)LE * 4);
  short* eW1P = (short*)carve((size_t)256 * 128 * 2);
  short* eW2P = (short*)carve((size_t)128 * 256 * 2);
  short* nW1P = (short*)carve((size_t)256 * 128 * 2);
  short* nW2P = (short*)carve((size_t)128 * 256 * 2);
  (void)ws_size;
  (void)n_in;
  (void)out_size;

  // h lives in the (fp32-sized) output region as bf16; dead before mlp writes.
  auto run_layer = [&](const float* x, const int* ei, int M, int nnz, const float* eattr,
                       const float** P, short* W1P, short* W2P, float* outp) {
    const int* src = ei;
    const int* dst = ei + nnz;
    __hip_bfloat16* h = (__hip_bfloat16*)outp;
    hipMemsetAsync(counts, 0, (size_t)M * 4, stream);
    wprep_kernel<<<256, 128, 0, stream>>>(P[3], W1P, 128, 256);
    wprep_kernel<<<128, 256, 0, stream>>>(P[7], W2P, 256, 128);
    ln_relu_kernel<<<(M + 3) / 4, 256, 0, stream>>>(x, P[0], P[1], h, M);
    count_kernel<<<(nnz + 255) / 256, 256, 0, stream>>>(dst, counts, nnz);
    int nb = (M + 1023) / 1024;
    scan_block_sums<<<nb, 256, 0, stream>>>(counts, bsums, M);
    scan_bsums<<<1, 512, 0, stream>>>(bsums, nb);
    scan_write<<<nb, 256, 0, stream>>>(counts, bsums, off, cursor, M, nnz);
    if (eattr) {
      fill_kernel<true><<<(nnz + 255) / 256, 256, 0, stream>>>(src, dst, cursor, csr_src,
                                                               csr_eid, nnz);
      aggregate_kernel<true><<<(M + 3) / 4, 256, 0, stream>>>(h, off, csr_src, csr_eid,
                                                              eattr, P[2], (uint*)yPbuf, M);
    } else {
      fill_kernel<false><<<(nnz + 255) / 256, 256, 0, stream>>>(src, dst, cursor, csr_src,
                                                                csr_eid, nnz);
      aggregate_kernel<false><<<(M + 3) / 4, 256, 0, stream>>>(h, off, csr_src, csr_eid,
                                                               nullptr, P[2], (uint*)yPbuf, M);
    }
    mlp_kernel<<<(M + 31) / 32, 256, 0, stream>>>(x, yPbuf, W1P, P[4], P[5], P[6], W2P,
                                                  P[8], outp, M);
  };

  run_layer(e_x, e_ei, E, LE, nullptr, ep, eW1P, eW2P, e_out);
  run_layer(v_x, v_ei, N, E, e_out, np_, nW1P, nW2P, v_out);
}